// Round 1
// baseline (527.848 us; speedup 1.0000x reference)
//
#include <hip/hip_runtime.h>
#include <math.h>

#define N 1024
#define H 256
#define L 512
#define NG 50
#define NI 3
#define B 16
#define NB 2048            // distance-LUT bins over [0, CUT]
#define CUT 5.0f
#define BPB 8              // bins per block in table_k

__device__ __forceinline__ float gelu_f(float x) {
    return 0.5f * x * (1.0f + erff(x * 0.70710678118654752f));
}

__global__ void embed_k(const int* __restrict__ z, const float* __restrict__ emb,
                        float* __restrict__ h) {
    int i = blockIdx.x, c = threadIdx.x;
    h[i * H + c] = emb[z[i] * H + c];
}

// Build W_tab[b][c], b in [0, NB], d_b = b * CUT/NB.
// W(d) = gelu(rbf(d) @ fw1 + fb1) @ fw2 + fb2
__global__ void table_k(const float* __restrict__ fw1, const float* __restrict__ fb1,
                        const float* __restrict__ fw2, const float* __restrict__ fb2,
                        float* __restrict__ Wt) {
    int b0 = blockIdx.x * BPB;
    int c = threadIdx.x;
    __shared__ float sRbf[BPB][NG];
    __shared__ float sG[BPB][H];
    const float delta = CUT / (float)NB;
    if (c < NG) {
        float center = c * (CUT / 49.0f);          // linspace(0,5,50)
        for (int u = 0; u < BPB; ++u) {
            float d = (float)(b0 + u) * delta;
            float t = d - center;
            sRbf[u][c] = expf(t * t * -200.0f);    // -1/(2*0.05^2)
        }
    }
    __syncthreads();
    float pre[BPB];
    float bias1 = fb1[c];
    #pragma unroll
    for (int u = 0; u < BPB; ++u) pre[u] = bias1;
    for (int k = 0; k < NG; ++k) {
        float w = fw1[k * H + c];
        #pragma unroll
        for (int u = 0; u < BPB; ++u) pre[u] = fmaf(sRbf[u][k], w, pre[u]);
    }
    #pragma unroll
    for (int u = 0; u < BPB; ++u) sG[u][c] = gelu_f(pre[u]);
    __syncthreads();
    float out[BPB];
    float bias2 = fb2[c];
    #pragma unroll
    for (int u = 0; u < BPB; ++u) out[u] = bias2;
    for (int k = 0; k < H; ++k) {
        float w = fw2[k * H + c];
        #pragma unroll
        for (int u = 0; u < BPB; ++u) out[u] = fmaf(sG[u][k], w, out[u]);
    }
    #pragma unroll
    for (int u = 0; u < BPB; ++u) {
        int b = b0 + u;
        if (b <= NB) Wt[b * H + c] = out[u];
    }
}

// Fused: neighbor list -> agg[i,:] via LUT lerp -> atom MLP -> residual.
__global__ void __launch_bounds__(256) pair_k(
    const float* __restrict__ pos, const float* __restrict__ hin,
    const float* __restrict__ Wt,
    const float* __restrict__ aw1, const float* __restrict__ ab1,
    const float* __restrict__ aw2, const float* __restrict__ ab2,
    float* __restrict__ hout) {
    int i = blockIdx.x;
    int c = threadIdx.x;
    __shared__ int sCnt;
    __shared__ int sPk[N];
    __shared__ float sFr[N];
    __shared__ float sVec[H];
    if (c == 0) sCnt = 0;
    __syncthreads();
    float pix = pos[i * 3 + 0], piy = pos[i * 3 + 1], piz = pos[i * 3 + 2];
    const float invd = (float)NB / CUT;
    for (int r = 0; r < N / 256; ++r) {
        int j = c + r * 256;
        float dx = pos[j * 3 + 0] - pix;
        float dy = pos[j * 3 + 1] - piy;
        float dz = pos[j * 3 + 2] - piz;
        float d = sqrtf(dx * dx + dy * dy + dz * dz);
        if (d < CUT && d > 1e-6f) {
            float u = d * invd;
            int bin = (int)u;
            if (bin > NB - 1) bin = NB - 1;
            float fr = u - (float)bin;
            int idx = atomicAdd(&sCnt, 1);
            sPk[idx] = j | (bin << 10);
            sFr[idx] = fr;
        }
    }
    __syncthreads();
    int cnt = sCnt;
    float acc = 0.0f;
    #pragma unroll 4
    for (int n = 0; n < cnt; ++n) {
        int p = sPk[n];
        float t = sFr[n];
        int j = p & 1023;
        int bin = p >> 10;
        const float* w = Wt + bin * H + c;
        float w0 = w[0];
        float w1 = w[H];
        acc = fmaf(fmaf(t, w1 - w0, w0), hin[j * H + c], acc);
    }
    // atom MLP: gelu(agg@aw1+ab1)@aw2+ab2, residual add
    sVec[c] = acc;
    __syncthreads();
    float t1 = ab1[c];
    for (int k = 0; k < H; ++k) t1 = fmaf(sVec[k], aw1[k * H + c], t1);
    float g = gelu_f(t1);
    __syncthreads();
    sVec[c] = g;
    __syncthreads();
    float t2 = ab2[c];
    for (int k = 0; k < H; ++k) t2 = fmaf(sVec[k], aw2[k * H + c], t2);
    hout[i * H + c] = hin[i * H + c] + t2;
}

// pooled -> gelu(pw1) -> pw2 -> layernorm. Block per molecule (64 atoms).
__global__ void head_k(const float* __restrict__ h,
                       const float* __restrict__ pw1, const float* __restrict__ pb1,
                       const float* __restrict__ pw2, const float* __restrict__ pb2,
                       const float* __restrict__ ln_g, const float* __restrict__ ln_b,
                       float* __restrict__ out) {
    int b = blockIdx.x, c = threadIdx.x;
    __shared__ float sP[H];
    __shared__ float sG[H];
    __shared__ float sX[L];
    __shared__ float sRed[256];
    float p = 0.0f;
    for (int a = 0; a < 64; ++a) p += h[(b * 64 + a) * H + c];
    sP[c] = p;
    __syncthreads();
    float t1 = pb1[c];
    for (int k = 0; k < H; ++k) t1 = fmaf(sP[k], pw1[k * H + c], t1);
    sG[c] = gelu_f(t1);
    __syncthreads();
    for (int r = 0; r < 2; ++r) {
        int l = c + r * 256;
        float x = pb2[l];
        for (int k = 0; k < H; ++k) x = fmaf(sG[k], pw2[k * L + l], x);
        sX[l] = x;
    }
    __syncthreads();
    sRed[c] = sX[c] + sX[c + 256];
    __syncthreads();
    for (int off = 128; off > 0; off >>= 1) {
        if (c < off) sRed[c] += sRed[c + off];
        __syncthreads();
    }
    float mu = sRed[0] / (float)L;
    __syncthreads();
    float d0 = sX[c] - mu, d1 = sX[c + 256] - mu;
    sRed[c] = d0 * d0 + d1 * d1;
    __syncthreads();
    for (int off = 128; off > 0; off >>= 1) {
        if (c < off) sRed[c] += sRed[c + off];
        __syncthreads();
    }
    float var = sRed[0] / (float)L;
    float rstd = rsqrtf(var + 1e-5f);
    for (int r = 0; r < 2; ++r) {
        int l = c + r * 256;
        out[b * L + l] = (sX[l] - mu) * rstd * ln_g[l] + ln_b[l];
    }
}

extern "C" void kernel_launch(void* const* d_in, const int* in_sizes, int n_in,
                              void* d_out, int out_size, void* d_ws, size_t ws_size,
                              hipStream_t stream) {
    const int*   z    = (const int*)d_in[0];
    const float* pos  = (const float*)d_in[1];
    // d_in[2] = batch: fixed arange//64 layout, handled implicitly in head_k
    const float* emb  = (const float*)d_in[3];
    const float* fw1  = (const float*)d_in[4];
    const float* fb1  = (const float*)d_in[5];
    const float* fw2  = (const float*)d_in[6];
    const float* fb2  = (const float*)d_in[7];
    const float* aw1  = (const float*)d_in[8];
    const float* ab1  = (const float*)d_in[9];
    const float* aw2  = (const float*)d_in[10];
    const float* ab2  = (const float*)d_in[11];
    const float* pw1  = (const float*)d_in[12];
    const float* pb1  = (const float*)d_in[13];
    const float* pw2  = (const float*)d_in[14];
    const float* pb2  = (const float*)d_in[15];
    const float* ln_g = (const float*)d_in[16];
    const float* ln_b = (const float*)d_in[17];
    float* out = (float*)d_out;

    float* hA = (float*)d_ws;
    float* hB = hA + N * H;
    float* Wt = hB + N * H;   // (NB+1) * H floats

    embed_k<<<N, H, 0, stream>>>(z, emb, hA);
    float* hin = hA;
    float* hout = hB;
    for (int it = 0; it < NI; ++it) {
        table_k<<<(NB + 1 + BPB - 1) / BPB, 256, 0, stream>>>(
            fw1 + it * NG * H, fb1 + it * H, fw2 + it * H * H, fb2 + it * H, Wt);
        pair_k<<<N, 256, 0, stream>>>(pos, hin, Wt, aw1 + it * H * H, ab1 + it * H,
                                      aw2 + it * H * H, ab2 + it * H, hout);
        float* tmp = hin; hin = hout; hout = tmp;
    }
    head_k<<<B, 256, 0, stream>>>(hin, pw1, pb1, pw2, pb2, ln_g, ln_b, out);
}

// Round 2
// 497.659 us; speedup vs baseline: 1.0607x; 1.0607x over previous
//
#include <hip/hip_runtime.h>
#include <math.h>

#define N 1024
#define H 256
#define L 512
#define NG 50
#define NI 3
#define B 16
#define NB 2048            // distance-LUT bins over [0, CUT]
#define CUT 5.0f
#define BPB 32             // bins per block in table_k
#define TROWS (NB + 1)     // 2049 rows per table
#define MLPG 8             // atoms per block in mlp_k

__device__ __forceinline__ float gelu_f(float x) {
    return 0.5f * x * (1.0f + erff(x * 0.70710678118654752f));
}

__global__ void embed_k(const int* __restrict__ z, const float* __restrict__ emb,
                        float* __restrict__ h) {
    int i = blockIdx.x, c = threadIdx.x;
    h[i * H + c] = emb[z[i] * H + c];
}

// Build all NI tables in one launch. grid = NI * ceil(TROWS/BPB) = 3*65.
// Wt[layer][b][c], d_b = b * CUT/NB.  W(d) = gelu(rbf(d)@fw1+fb1)@fw2+fb2
__global__ void __launch_bounds__(256) table_k(
        const float* __restrict__ fw1, const float* __restrict__ fb1,
        const float* __restrict__ fw2, const float* __restrict__ fb2,
        float* __restrict__ Wt) {
    const int bpl = (TROWS + BPB - 1) / BPB;      // 65 blocks per layer
    int layer = blockIdx.x / bpl;
    int blk = blockIdx.x % bpl;
    int b0 = blk * BPB;
    int c = threadIdx.x;
    const float* lfw1 = fw1 + layer * NG * H;
    const float* lfw2 = fw2 + layer * H * H;
    float* lWt = Wt + (size_t)layer * TROWS * H;

    __shared__ float sRbf[BPB][NG];
    __shared__ float sG[BPB][H];
    const float delta = CUT / (float)NB;
    if (c < NG) {
        float center = c * (CUT / 49.0f);          // linspace(0,5,50)
        #pragma unroll
        for (int u = 0; u < BPB; ++u) {
            float d = (float)(b0 + u) * delta;
            float t = d - center;
            sRbf[u][c] = expf(t * t * -200.0f);    // -1/(2*0.05^2)
        }
    }
    __syncthreads();
    float pre[BPB];
    float bias1 = fb1[layer * H + c];
    #pragma unroll
    for (int u = 0; u < BPB; ++u) pre[u] = bias1;
    for (int k = 0; k < NG; ++k) {
        float w = lfw1[k * H + c];
        #pragma unroll
        for (int u = 0; u < BPB; ++u) pre[u] = fmaf(sRbf[u][k], w, pre[u]);
    }
    #pragma unroll
    for (int u = 0; u < BPB; ++u) sG[u][c] = gelu_f(pre[u]);
    __syncthreads();
    float out[BPB];
    float bias2 = fb2[layer * H + c];
    #pragma unroll
    for (int u = 0; u < BPB; ++u) out[u] = bias2;
    #pragma unroll 2
    for (int k = 0; k < H; ++k) {
        float w = lfw2[k * H + c];
        #pragma unroll
        for (int u = 0; u < BPB; ++u) out[u] = fmaf(sG[u][k], w, out[u]);
    }
    #pragma unroll
    for (int u = 0; u < BPB; ++u) {
        int b = b0 + u;
        if (b < TROWS) lWt[b * H + c] = out[u];
    }
}

// Aggregation: agg[i,c] = sum_j lerp(Wt, d_ij)[c] * hin[j,c] over neighbors.
// Block = 256 thr = 4 waves = 2 atoms; waves (2a, 2a+1) split atom a's
// neighbor list by parity. Lane l owns channels 4l..4l+3 (float4).
__global__ void __launch_bounds__(256) pair_k(
    const float* __restrict__ pos, const float* __restrict__ hin,
    const float* __restrict__ Wt, float* __restrict__ agg) {
    int c = threadIdx.x;
    int wid = c >> 6;          // wave 0..3
    int lane = c & 63;
    int a = wid >> 1;          // atom slot 0/1 within block
    int par = wid & 1;         // neighbor parity for this wave
    int i = blockIdx.x * 2 + a;

    __shared__ int sCnt[2];
    __shared__ int sPk[2][N];     // j | (bin<<10)
    __shared__ float sFr[2][N];
    __shared__ float sPart[4][H];
    if (c < 2) sCnt[c] = 0;
    __syncthreads();

    float pix = pos[i * 3 + 0], piy = pos[i * 3 + 1], piz = pos[i * 3 + 2];
    const float invd = (float)NB / CUT;
    // both waves of the atom build the list together: wave covers half of j
    for (int r = 0; r < N / 128; ++r) {
        int j = lane + (par * (N / 128) + r) * 64;
        float dx = pos[j * 3 + 0] - pix;
        float dy = pos[j * 3 + 1] - piy;
        float dz = pos[j * 3 + 2] - piz;
        float d = sqrtf(dx * dx + dy * dy + dz * dz);
        if (d < CUT && d > 1e-6f) {
            float u = d * invd;
            int bin = (int)u;
            float fr = u - (float)bin;
            int idx = atomicAdd(&sCnt[a], 1);
            sPk[a][idx] = j | (bin << 10);
            sFr[a][idx] = fr;
        }
    }
    __syncthreads();
    int cnt = sCnt[a];
    float4 acc = make_float4(0.f, 0.f, 0.f, 0.f);
    #pragma unroll 4
    for (int n = par; n < cnt; n += 2) {
        int p = sPk[a][n];
        float t = sFr[a][n];
        int j = p & 1023;
        int bin = p >> 10;
        const float4* w = (const float4*)(Wt + bin * H) + lane;
        float4 w0 = w[0];
        float4 w1 = w[H / 4];
        float4 hv = ((const float4*)(hin + j * H))[lane];
        acc.x = fmaf(fmaf(t, w1.x - w0.x, w0.x), hv.x, acc.x);
        acc.y = fmaf(fmaf(t, w1.y - w0.y, w0.y), hv.y, acc.y);
        acc.z = fmaf(fmaf(t, w1.z - w0.z, w0.z), hv.z, acc.z);
        acc.w = fmaf(fmaf(t, w1.w - w0.w, w0.w), hv.w, acc.w);
    }
    ((float4*)sPart[wid])[lane] = acc;
    __syncthreads();
    // combine partials, write agg for both atoms
    agg[(blockIdx.x * 2 + 0) * H + c] = sPart[0][c] + sPart[1][c];
    agg[(blockIdx.x * 2 + 1) * H + c] = sPart[2][c] + sPart[3][c];
}

// Atom MLP: hout = hin + gelu(agg@aw1+ab1)@aw2+ab2. MLPG atoms per block.
__global__ void __launch_bounds__(256) mlp_k(
    const float* __restrict__ agg, const float* __restrict__ hin,
    const float* __restrict__ aw1, const float* __restrict__ ab1,
    const float* __restrict__ aw2, const float* __restrict__ ab2,
    float* __restrict__ hout) {
    int c = threadIdx.x;
    int i0 = blockIdx.x * MLPG;
    __shared__ float sA[MLPG][H];
    __shared__ float sG[MLPG][H];
    #pragma unroll
    for (int a = 0; a < MLPG; ++a) sA[a][c] = agg[(i0 + a) * H + c];
    __syncthreads();
    float t1[MLPG];
    float b1 = ab1[c];
    #pragma unroll
    for (int a = 0; a < MLPG; ++a) t1[a] = b1;
    #pragma unroll 2
    for (int k = 0; k < H; ++k) {
        float w = aw1[k * H + c];
        #pragma unroll
        for (int a = 0; a < MLPG; ++a) t1[a] = fmaf(sA[a][k], w, t1[a]);
    }
    #pragma unroll
    for (int a = 0; a < MLPG; ++a) sG[a][c] = gelu_f(t1[a]);
    __syncthreads();
    float t2[MLPG];
    float b2 = ab2[c];
    #pragma unroll
    for (int a = 0; a < MLPG; ++a) t2[a] = b2;
    #pragma unroll 2
    for (int k = 0; k < H; ++k) {
        float w = aw2[k * H + c];
        #pragma unroll
        for (int a = 0; a < MLPG; ++a) t2[a] = fmaf(sG[a][k], w, t2[a]);
    }
    #pragma unroll
    for (int a = 0; a < MLPG; ++a)
        hout[(i0 + a) * H + c] = hin[(i0 + a) * H + c] + t2[a];
}

// pooled -> gelu(pw1) -> pw2 -> layernorm. Block per molecule (64 atoms).
__global__ void head_k(const float* __restrict__ h,
                       const float* __restrict__ pw1, const float* __restrict__ pb1,
                       const float* __restrict__ pw2, const float* __restrict__ pb2,
                       const float* __restrict__ ln_g, const float* __restrict__ ln_b,
                       float* __restrict__ out) {
    int b = blockIdx.x, c = threadIdx.x;
    __shared__ float sP[H];
    __shared__ float sG[H];
    __shared__ float sX[L];
    __shared__ float sRed[256];
    float p = 0.0f;
    for (int a = 0; a < 64; ++a) p += h[(b * 64 + a) * H + c];
    sP[c] = p;
    __syncthreads();
    float t1 = pb1[c];
    for (int k = 0; k < H; ++k) t1 = fmaf(sP[k], pw1[k * H + c], t1);
    sG[c] = gelu_f(t1);
    __syncthreads();
    for (int r = 0; r < 2; ++r) {
        int l = c + r * 256;
        float x = pb2[l];
        for (int k = 0; k < H; ++k) x = fmaf(sG[k], pw2[k * L + l], x);
        sX[l] = x;
    }
    __syncthreads();
    sRed[c] = sX[c] + sX[c + 256];
    __syncthreads();
    for (int off = 128; off > 0; off >>= 1) {
        if (c < off) sRed[c] += sRed[c + off];
        __syncthreads();
    }
    float mu = sRed[0] / (float)L;
    __syncthreads();
    float d0 = sX[c] - mu, d1 = sX[c + 256] - mu;
    sRed[c] = d0 * d0 + d1 * d1;
    __syncthreads();
    for (int off = 128; off > 0; off >>= 1) {
        if (c < off) sRed[c] += sRed[c + off];
        __syncthreads();
    }
    float var = sRed[0] / (float)L;
    float rstd = rsqrtf(var + 1e-5f);
    for (int r = 0; r < 2; ++r) {
        int l = c + r * 256;
        out[b * L + l] = (sX[l] - mu) * rstd * ln_g[l] + ln_b[l];
    }
}

extern "C" void kernel_launch(void* const* d_in, const int* in_sizes, int n_in,
                              void* d_out, int out_size, void* d_ws, size_t ws_size,
                              hipStream_t stream) {
    const int*   z    = (const int*)d_in[0];
    const float* pos  = (const float*)d_in[1];
    // d_in[2] = batch: fixed arange//64 layout, handled implicitly in head_k
    const float* emb  = (const float*)d_in[3];
    const float* fw1  = (const float*)d_in[4];
    const float* fb1  = (const float*)d_in[5];
    const float* fw2  = (const float*)d_in[6];
    const float* fb2  = (const float*)d_in[7];
    const float* aw1  = (const float*)d_in[8];
    const float* ab1  = (const float*)d_in[9];
    const float* aw2  = (const float*)d_in[10];
    const float* ab2  = (const float*)d_in[11];
    const float* pw1  = (const float*)d_in[12];
    const float* pb1  = (const float*)d_in[13];
    const float* pw2  = (const float*)d_in[14];
    const float* pb2  = (const float*)d_in[15];
    const float* ln_g = (const float*)d_in[16];
    const float* ln_b = (const float*)d_in[17];
    float* out = (float*)d_out;

    float* hA  = (float*)d_ws;                    // [N][H]
    float* hB  = hA + N * H;                      // [N][H]
    float* Wt  = hB + N * H;                      // [NI][TROWS][H]
    float* agg = Wt + (size_t)NI * TROWS * H;     // [N][H]

    embed_k<<<N, H, 0, stream>>>(z, emb, hA);
    {
        int bpl = (TROWS + BPB - 1) / BPB;
        table_k<<<NI * bpl, 256, 0, stream>>>(fw1, fb1, fw2, fb2, Wt);
    }
    float* hin = hA;
    float* hout = hB;
    for (int it = 0; it < NI; ++it) {
        pair_k<<<N / 2, 256, 0, stream>>>(pos, hin, Wt + (size_t)it * TROWS * H, agg);
        mlp_k<<<N / MLPG, 256, 0, stream>>>(agg, hin, aw1 + it * H * H, ab1 + it * H,
                                            aw2 + it * H * H, ab2 + it * H, hout);
        float* tmp = hin; hin = hout; hout = tmp;
    }
    head_k<<<B, 256, 0, stream>>>(hin, pw1, pb1, pw2, pb2, ln_g, ln_b, out);
}

// Round 3
// 316.553 us; speedup vs baseline: 1.6675x; 1.5721x over previous
//
#include <hip/hip_runtime.h>
#include <math.h>

#define N 1024
#define H 256
#define L 512
#define NG 50
#define NI 3
#define B 16
#define NB 2048            // distance-LUT bins over [0, CUT]
#define CUT 5.0f
#define BPB 32             // bins per block in table_k (8 per wave)
#define TROWS (NB + 1)     // 2049 rows per table
#define MATB 4             // atoms per block in mlp_k

__device__ __forceinline__ float gelu_f(float x) {
    return 0.5f * x * (1.0f + erff(x * 0.70710678118654752f));
}

__global__ void embed_k(const int* __restrict__ z, const float* __restrict__ emb,
                        float* __restrict__ h) {
    int i = blockIdx.x, c = threadIdx.x;
    h[i * H + c] = emb[z[i] * H + c];
}

// Build all NI tables in one launch. grid = NI * ceil(TROWS/BPB) = 3*65.
// Thread owns 4 channels (float4) x 8 bins; wave owns bins [8*wid, 8*wid+8).
__global__ void __launch_bounds__(256) table_k(
        const float* __restrict__ fw1, const float* __restrict__ fb1,
        const float* __restrict__ fw2, const float* __restrict__ fb2,
        float* __restrict__ Wt) {
    const int bpl = (TROWS + BPB - 1) / BPB;      // 65 blocks per layer
    int layer = blockIdx.x / bpl;
    int blk = blockIdx.x % bpl;
    int b0 = blk * BPB;
    int tid = threadIdx.x;
    int wid = tid >> 6, lane = tid & 63;
    int c4 = lane * 4;
    int u0 = wid * 8;
    const float* lfw1 = fw1 + layer * NG * H;
    const float* lfw2 = fw2 + layer * H * H;
    float* lWt = Wt + (size_t)layer * TROWS * H;

    __shared__ float sRbf[BPB][NG];
    __shared__ __align__(16) float sG[BPB][H];
    const float delta = CUT / (float)NB;
    for (int idx = tid; idx < BPB * NG; idx += 256) {
        int u = idx & 31;
        int k = idx >> 5;
        float d = (float)(b0 + u) * delta;
        float t = d - (float)k * (CUT / 49.0f);   // centers = linspace(0,5,50)
        sRbf[u][k] = expf(t * t * -200.0f);       // -1/(2*0.05^2)
    }
    __syncthreads();

    // layer 1: rbf @ fw1, k over NG
    float4 acc1[8];
    #pragma unroll
    for (int u = 0; u < 8; ++u) acc1[u] = make_float4(0.f, 0.f, 0.f, 0.f);
    #pragma unroll 2
    for (int k = 0; k < NG; ++k) {
        float4 w = *(const float4*)(lfw1 + k * H + c4);
        #pragma unroll
        for (int u = 0; u < 8; ++u) {
            float r = sRbf[u0 + u][k];
            acc1[u].x = fmaf(r, w.x, acc1[u].x);
            acc1[u].y = fmaf(r, w.y, acc1[u].y);
            acc1[u].z = fmaf(r, w.z, acc1[u].z);
            acc1[u].w = fmaf(r, w.w, acc1[u].w);
        }
    }
    float4 b1 = *(const float4*)(fb1 + layer * H + c4);
    #pragma unroll
    for (int u = 0; u < 8; ++u) {
        float4 g;
        g.x = gelu_f(acc1[u].x + b1.x);
        g.y = gelu_f(acc1[u].y + b1.y);
        g.z = gelu_f(acc1[u].z + b1.z);
        g.w = gelu_f(acc1[u].w + b1.w);
        *(float4*)&sG[u0 + u][c4] = g;            // wave-private rows
    }
    __syncthreads();

    // layer 2: sG @ fw2, k over H
    float4 acc2[8];
    #pragma unroll
    for (int u = 0; u < 8; ++u) acc2[u] = make_float4(0.f, 0.f, 0.f, 0.f);
    #pragma unroll 2
    for (int k = 0; k < H; ++k) {
        float4 w = *(const float4*)(lfw2 + k * H + c4);
        #pragma unroll
        for (int u = 0; u < 8; ++u) {
            float g = sG[u0 + u][k];
            acc2[u].x = fmaf(g, w.x, acc2[u].x);
            acc2[u].y = fmaf(g, w.y, acc2[u].y);
            acc2[u].z = fmaf(g, w.z, acc2[u].z);
            acc2[u].w = fmaf(g, w.w, acc2[u].w);
        }
    }
    float4 b2 = *(const float4*)(fb2 + layer * H + c4);
    #pragma unroll
    for (int u = 0; u < 8; ++u) {
        int b = b0 + u0 + u;
        if (b < TROWS) {
            float4 v;
            v.x = acc2[u].x + b2.x;
            v.y = acc2[u].y + b2.y;
            v.z = acc2[u].z + b2.z;
            v.w = acc2[u].w + b2.w;
            *(float4*)&lWt[b * H + c4] = v;
        }
    }
}

// Aggregation: agg[i,c] = sum_j lerp(Wt, d_ij)[c] * hin[j,c] over neighbors.
// Block = 256 thr = 4 waves = 2 atoms; waves (2a, 2a+1) split atom a's
// neighbor list by parity. Lane l owns channels 4l..4l+3 (float4).
__global__ void __launch_bounds__(256) pair_k(
    const float* __restrict__ pos, const float* __restrict__ hin,
    const float* __restrict__ Wt, float* __restrict__ agg) {
    int c = threadIdx.x;
    int wid = c >> 6;          // wave 0..3
    int lane = c & 63;
    int a = wid >> 1;          // atom slot 0/1 within block
    int par = wid & 1;         // neighbor parity for this wave
    int i = blockIdx.x * 2 + a;

    __shared__ int sCnt[2];
    __shared__ int sPk[2][N];     // j | (bin<<10)
    __shared__ float sFr[2][N];
    __shared__ float sPart[4][H];
    if (c < 2) sCnt[c] = 0;
    __syncthreads();

    float pix = pos[i * 3 + 0], piy = pos[i * 3 + 1], piz = pos[i * 3 + 2];
    const float invd = (float)NB / CUT;
    for (int r = 0; r < N / 128; ++r) {
        int j = lane + (par * (N / 128) + r) * 64;
        float dx = pos[j * 3 + 0] - pix;
        float dy = pos[j * 3 + 1] - piy;
        float dz = pos[j * 3 + 2] - piz;
        float d = sqrtf(dx * dx + dy * dy + dz * dz);
        if (d < CUT && d > 1e-6f) {
            float u = d * invd;
            int bin = (int)u;
            float fr = u - (float)bin;
            int idx = atomicAdd(&sCnt[a], 1);
            sPk[a][idx] = j | (bin << 10);
            sFr[a][idx] = fr;
        }
    }
    __syncthreads();
    int cnt = sCnt[a];
    float4 acc = make_float4(0.f, 0.f, 0.f, 0.f);
    #pragma unroll 4
    for (int n = par; n < cnt; n += 2) {
        int p = sPk[a][n];
        float t = sFr[a][n];
        int j = p & 1023;
        int bin = p >> 10;
        const float4* w = (const float4*)(Wt + bin * H) + lane;
        float4 w0 = w[0];
        float4 w1 = w[H / 4];
        float4 hv = ((const float4*)(hin + j * H))[lane];
        acc.x = fmaf(fmaf(t, w1.x - w0.x, w0.x), hv.x, acc.x);
        acc.y = fmaf(fmaf(t, w1.y - w0.y, w0.y), hv.y, acc.y);
        acc.z = fmaf(fmaf(t, w1.z - w0.z, w0.z), hv.z, acc.z);
        acc.w = fmaf(fmaf(t, w1.w - w0.w, w0.w), hv.w, acc.w);
    }
    ((float4*)sPart[wid])[lane] = acc;
    __syncthreads();
    agg[(blockIdx.x * 2 + 0) * H + c] = sPart[0][c] + sPart[1][c];
    agg[(blockIdx.x * 2 + 1) * H + c] = sPart[2][c] + sPart[3][c];
}

// Atom MLP: hout = hin + gelu(agg@aw1+ab1)@aw2+ab2.
// 4 atoms/block, grid N/4=256. Waves split K into quarters; lane owns 4
// channels (float4); partials combined through LDS.
__global__ void __launch_bounds__(256) mlp_k(
    const float* __restrict__ agg, const float* __restrict__ hin,
    const float* __restrict__ aw1, const float* __restrict__ ab1,
    const float* __restrict__ aw2, const float* __restrict__ ab2,
    float* __restrict__ hout) {
    int tid = threadIdx.x;
    int wid = tid >> 6, lane = tid & 63;
    int c4 = lane * 4;
    int i0 = blockIdx.x * MATB;
    __shared__ __align__(16) float sAT[H][MATB];   // acts transposed [k][a]
    __shared__ __align__(16) float sGT[H][MATB];
    __shared__ __align__(16) float sPart[4][MATB][H];

    #pragma unroll
    for (int r = 0; r < MATB; ++r)
        sAT[tid][r] = agg[(i0 + r) * H + tid];
    __syncthreads();

    int k0 = wid * 64;
    float4 acc[MATB];
    #pragma unroll
    for (int a = 0; a < MATB; ++a) acc[a] = make_float4(0.f, 0.f, 0.f, 0.f);
    #pragma unroll 8
    for (int k = 0; k < 64; ++k) {
        float4 w = *(const float4*)(aw1 + (k0 + k) * H + c4);
        float4 act = *(const float4*)&sAT[k0 + k][0];
        acc[0].x = fmaf(act.x, w.x, acc[0].x); acc[0].y = fmaf(act.x, w.y, acc[0].y);
        acc[0].z = fmaf(act.x, w.z, acc[0].z); acc[0].w = fmaf(act.x, w.w, acc[0].w);
        acc[1].x = fmaf(act.y, w.x, acc[1].x); acc[1].y = fmaf(act.y, w.y, acc[1].y);
        acc[1].z = fmaf(act.y, w.z, acc[1].z); acc[1].w = fmaf(act.y, w.w, acc[1].w);
        acc[2].x = fmaf(act.z, w.x, acc[2].x); acc[2].y = fmaf(act.z, w.y, acc[2].y);
        acc[2].z = fmaf(act.z, w.z, acc[2].z); acc[2].w = fmaf(act.z, w.w, acc[2].w);
        acc[3].x = fmaf(act.w, w.x, acc[3].x); acc[3].y = fmaf(act.w, w.y, acc[3].y);
        acc[3].z = fmaf(act.w, w.z, acc[3].z); acc[3].w = fmaf(act.w, w.w, acc[3].w);
    }
    #pragma unroll
    for (int a = 0; a < MATB; ++a)
        *(float4*)&sPart[wid][a][c4] = acc[a];
    __syncthreads();
    {
        float b1 = ab1[tid];
        float g[MATB];
        #pragma unroll
        for (int a = 0; a < MATB; ++a) {
            float v = b1 + sPart[0][a][tid] + sPart[1][a][tid]
                         + sPart[2][a][tid] + sPart[3][a][tid];
            g[a] = gelu_f(v);
        }
        *(float4*)&sGT[tid][0] = make_float4(g[0], g[1], g[2], g[3]);
    }
    __syncthreads();
    #pragma unroll
    for (int a = 0; a < MATB; ++a) acc[a] = make_float4(0.f, 0.f, 0.f, 0.f);
    #pragma unroll 8
    for (int k = 0; k < 64; ++k) {
        float4 w = *(const float4*)(aw2 + (k0 + k) * H + c4);
        float4 act = *(const float4*)&sGT[k0 + k][0];
        acc[0].x = fmaf(act.x, w.x, acc[0].x); acc[0].y = fmaf(act.x, w.y, acc[0].y);
        acc[0].z = fmaf(act.x, w.z, acc[0].z); acc[0].w = fmaf(act.x, w.w, acc[0].w);
        acc[1].x = fmaf(act.y, w.x, acc[1].x); acc[1].y = fmaf(act.y, w.y, acc[1].y);
        acc[1].z = fmaf(act.y, w.z, acc[1].z); acc[1].w = fmaf(act.y, w.w, acc[1].w);
        acc[2].x = fmaf(act.z, w.x, acc[2].x); acc[2].y = fmaf(act.z, w.y, acc[2].y);
        acc[2].z = fmaf(act.z, w.z, acc[2].z); acc[2].w = fmaf(act.z, w.w, acc[2].w);
        acc[3].x = fmaf(act.w, w.x, acc[3].x); acc[3].y = fmaf(act.w, w.y, acc[3].y);
        acc[3].z = fmaf(act.w, w.z, acc[3].z); acc[3].w = fmaf(act.w, w.w, acc[3].w);
    }
    #pragma unroll
    for (int a = 0; a < MATB; ++a)
        *(float4*)&sPart[wid][a][c4] = acc[a];
    __syncthreads();
    {
        float b2 = ab2[tid];
        #pragma unroll
        for (int a = 0; a < MATB; ++a) {
            float v = b2 + sPart[0][a][tid] + sPart[1][a][tid]
                         + sPart[2][a][tid] + sPart[3][a][tid];
            hout[(i0 + a) * H + tid] = hin[(i0 + a) * H + tid] + v;
        }
    }
}

// pooled -> gelu(pw1) -> pw2 -> layernorm. Block per molecule, waves split K.
__global__ void __launch_bounds__(256) head_k(
        const float* __restrict__ h,
        const float* __restrict__ pw1, const float* __restrict__ pb1,
        const float* __restrict__ pw2, const float* __restrict__ pb2,
        const float* __restrict__ ln_g, const float* __restrict__ ln_b,
        float* __restrict__ out) {
    int b = blockIdx.x, tid = threadIdx.x;
    int wid = tid >> 6, lane = tid & 63;
    int c4 = lane * 4;
    __shared__ float sP[H];
    __shared__ __align__(16) float sPw[4][H];
    __shared__ float sG[H];
    __shared__ __align__(16) float sP2[4][L];
    __shared__ float sX[L];
    __shared__ float sRed[256];

    // pooling: wave sums 16 atoms
    float4 p = make_float4(0.f, 0.f, 0.f, 0.f);
    #pragma unroll 4
    for (int a = 0; a < 16; ++a) {
        float4 hv = *(const float4*)(h + (b * 64 + wid * 16 + a) * H + c4);
        p.x += hv.x; p.y += hv.y; p.z += hv.z; p.w += hv.w;
    }
    *(float4*)&sPw[wid][c4] = p;
    __syncthreads();
    sP[tid] = sPw[0][tid] + sPw[1][tid] + sPw[2][tid] + sPw[3][tid];
    __syncthreads();

    // L1 GEMV: lane owns 4 channels, wave owns k-quarter
    int k0 = wid * 64;
    float4 acc = make_float4(0.f, 0.f, 0.f, 0.f);
    #pragma unroll 8
    for (int k = 0; k < 64; ++k) {
        float4 w = *(const float4*)(pw1 + (k0 + k) * H + c4);
        float s = sP[k0 + k];
        acc.x = fmaf(s, w.x, acc.x); acc.y = fmaf(s, w.y, acc.y);
        acc.z = fmaf(s, w.z, acc.z); acc.w = fmaf(s, w.w, acc.w);
    }
    *(float4*)&sPw[wid][c4] = acc;
    __syncthreads();
    sG[tid] = gelu_f(pb1[tid] + sPw[0][tid] + sPw[1][tid] + sPw[2][tid] + sPw[3][tid]);
    __syncthreads();

    // L2 GEMV: lane owns 8 outputs, wave owns k-quarter
    float4 a0 = make_float4(0.f, 0.f, 0.f, 0.f);
    float4 a1 = make_float4(0.f, 0.f, 0.f, 0.f);
    #pragma unroll 4
    for (int k = 0; k < 64; ++k) {
        float s = sG[k0 + k];
        float4 w0 = *(const float4*)(pw2 + (k0 + k) * L + lane * 8);
        float4 w1 = *(const float4*)(pw2 + (k0 + k) * L + lane * 8 + 4);
        a0.x = fmaf(s, w0.x, a0.x); a0.y = fmaf(s, w0.y, a0.y);
        a0.z = fmaf(s, w0.z, a0.z); a0.w = fmaf(s, w0.w, a0.w);
        a1.x = fmaf(s, w1.x, a1.x); a1.y = fmaf(s, w1.y, a1.y);
        a1.z = fmaf(s, w1.z, a1.z); a1.w = fmaf(s, w1.w, a1.w);
    }
    *(float4*)&sP2[wid][lane * 8] = a0;
    *(float4*)&sP2[wid][lane * 8 + 4] = a1;
    __syncthreads();
    for (int r = 0; r < 2; ++r) {
        int l = tid + r * 256;
        sX[l] = pb2[l] + sP2[0][l] + sP2[1][l] + sP2[2][l] + sP2[3][l];
    }
    __syncthreads();

    // layernorm
    sRed[tid] = sX[tid] + sX[tid + 256];
    __syncthreads();
    for (int off = 128; off > 0; off >>= 1) {
        if (tid < off) sRed[tid] += sRed[tid + off];
        __syncthreads();
    }
    float mu = sRed[0] / (float)L;
    __syncthreads();
    float d0 = sX[tid] - mu, d1 = sX[tid + 256] - mu;
    sRed[tid] = d0 * d0 + d1 * d1;
    __syncthreads();
    for (int off = 128; off > 0; off >>= 1) {
        if (tid < off) sRed[tid] += sRed[tid + off];
        __syncthreads();
    }
    float var = sRed[0] / (float)L;
    float rstd = rsqrtf(var + 1e-5f);
    for (int r = 0; r < 2; ++r) {
        int l = tid + r * 256;
        out[b * L + l] = (sX[l] - mu) * rstd * ln_g[l] + ln_b[l];
    }
}

extern "C" void kernel_launch(void* const* d_in, const int* in_sizes, int n_in,
                              void* d_out, int out_size, void* d_ws, size_t ws_size,
                              hipStream_t stream) {
    const int*   z    = (const int*)d_in[0];
    const float* pos  = (const float*)d_in[1];
    // d_in[2] = batch: fixed arange//64 layout, handled implicitly in head_k
    const float* emb  = (const float*)d_in[3];
    const float* fw1  = (const float*)d_in[4];
    const float* fb1  = (const float*)d_in[5];
    const float* fw2  = (const float*)d_in[6];
    const float* fb2  = (const float*)d_in[7];
    const float* aw1  = (const float*)d_in[8];
    const float* ab1  = (const float*)d_in[9];
    const float* aw2  = (const float*)d_in[10];
    const float* ab2  = (const float*)d_in[11];
    const float* pw1  = (const float*)d_in[12];
    const float* pb1  = (const float*)d_in[13];
    const float* pw2  = (const float*)d_in[14];
    const float* pb2  = (const float*)d_in[15];
    const float* ln_g = (const float*)d_in[16];
    const float* ln_b = (const float*)d_in[17];
    float* out = (float*)d_out;

    float* hA  = (float*)d_ws;                    // [N][H]
    float* hB  = hA + N * H;                      // [N][H]
    float* Wt  = hB + N * H;                      // [NI][TROWS][H]
    float* agg = Wt + (size_t)NI * TROWS * H;     // [N][H]

    embed_k<<<N, H, 0, stream>>>(z, emb, hA);
    {
        int bpl = (TROWS + BPB - 1) / BPB;
        table_k<<<NI * bpl, 256, 0, stream>>>(fw1, fb1, fw2, fb2, Wt);
    }
    float* hin = hA;
    float* hout = hB;
    for (int it = 0; it < NI; ++it) {
        pair_k<<<N / 2, 256, 0, stream>>>(pos, hin, Wt + (size_t)it * TROWS * H, agg);
        mlp_k<<<N / MATB, 256, 0, stream>>>(agg, hin, aw1 + it * H * H, ab1 + it * H,
                                            aw2 + it * H * H, ab2 + it * H, hout);
        float* tmp = hin; hin = hout; hout = tmp;
    }
    head_k<<<B, 256, 0, stream>>>(hin, pw1, pb1, pw2, pb2, ln_g, ln_b, out);
}

// Round 5
// 301.969 us; speedup vs baseline: 1.7480x; 1.0483x over previous
//
#include <hip/hip_runtime.h>
#include <math.h>

#define N 1024
#define H 256
#define L 512
#define NG 50
#define NI 3
#define B 16
#define NB 2048            // distance-LUT bins over [0, CUT]
#define CUT 5.0f
#define BPB 16             // bins per block in table_k (4 per wave)
#define TROWS (NB + 1)     // 2049 rows per table
#define MATB 4             // atoms per block in mlp_k

// NOTE: param must NOT be named 'w' — it would capture the '.w' member token.
#define FMA4(A_, S_, V_) do { \
    (A_).x = fmaf((S_), (V_).x, (A_).x); (A_).y = fmaf((S_), (V_).y, (A_).y); \
    (A_).z = fmaf((S_), (V_).z, (A_).z); (A_).w = fmaf((S_), (V_).w, (A_).w); } while (0)

__device__ __forceinline__ float gelu_f(float x) {
    return 0.5f * x * (1.0f + erff(x * 0.70710678118654752f));
}
__device__ __forceinline__ unsigned short f2bf(float f) {
    unsigned u = __float_as_uint(f);
    unsigned r = (u + 0x7fffu + ((u >> 16) & 1u)) >> 16;   // RNE
    return (unsigned short)r;
}
__device__ __forceinline__ float bf2f(unsigned short s) {
    return __uint_as_float((unsigned)s << 16);
}

__global__ void embed_k(const int* __restrict__ z, const float* __restrict__ emb,
                        float* __restrict__ h, unsigned short* __restrict__ hbf) {
    int i = blockIdx.x, c = threadIdx.x;
    float v = emb[z[i] * H + c];
    h[i * H + c] = v;
    hbf[i * H + c] = f2bf(v);
}

// Build all NI tables (bf16 output). grid = NI * ceil(TROWS/BPB) = 3*129.
// Wave owns 4 bins; lane owns 4 channels. LDS reads are broadcast b128 k-quads.
__global__ void __launch_bounds__(256) table_k(
        const float* __restrict__ fw1, const float* __restrict__ fb1,
        const float* __restrict__ fw2, const float* __restrict__ fb2,
        unsigned short* __restrict__ Wtb) {
    const int bpl = (TROWS + BPB - 1) / BPB;      // 129 blocks per layer
    int layer = blockIdx.x / bpl;
    int blk = blockIdx.x % bpl;
    int b0 = blk * BPB;
    int tid = threadIdx.x;
    int wid = tid >> 6, lane = tid & 63;
    int c4 = lane * 4;
    int ub = wid * 4;                             // wave's first bin slot
    const float* lfw1 = fw1 + layer * NG * H;
    const float* lfw2 = fw2 + layer * H * H;
    unsigned short* lWt = Wtb + (size_t)layer * TROWS * H;

    __shared__ __align__(16) float sRbf[BPB][56];  // 56: 16B-aligned rows
    __shared__ __align__(16) float sG[BPB][H];
    const float delta = CUT / (float)NB;
    for (int idx = tid; idx < BPB * NG; idx += 256) {
        int u = idx & 15;
        int k = idx >> 4;
        float d = (float)(b0 + u) * delta;
        float t = d - (float)k * (CUT / 49.0f);   // centers = linspace(0,5,50)
        sRbf[u][k] = expf(t * t * -200.0f);       // -1/(2*0.05^2)
    }
    __syncthreads();

    // layer 1: rbf @ fw1 (K = 50 = 12 quads + 2)
    float4 acc1[4];
    #pragma unroll
    for (int u = 0; u < 4; ++u) acc1[u] = make_float4(0.f, 0.f, 0.f, 0.f);
    for (int kq = 0; kq < 12; ++kq) {
        int k = kq * 4;
        float4 r0 = *(const float4*)&sRbf[ub + 0][k];
        float4 r1 = *(const float4*)&sRbf[ub + 1][k];
        float4 r2 = *(const float4*)&sRbf[ub + 2][k];
        float4 r3 = *(const float4*)&sRbf[ub + 3][k];
        float4 q0 = *(const float4*)(lfw1 + (k + 0) * H + c4);
        float4 q1 = *(const float4*)(lfw1 + (k + 1) * H + c4);
        float4 q2 = *(const float4*)(lfw1 + (k + 2) * H + c4);
        float4 q3 = *(const float4*)(lfw1 + (k + 3) * H + c4);
        FMA4(acc1[0], r0.x, q0); FMA4(acc1[0], r0.y, q1);
        FMA4(acc1[0], r0.z, q2); FMA4(acc1[0], r0.w, q3);
        FMA4(acc1[1], r1.x, q0); FMA4(acc1[1], r1.y, q1);
        FMA4(acc1[1], r1.z, q2); FMA4(acc1[1], r1.w, q3);
        FMA4(acc1[2], r2.x, q0); FMA4(acc1[2], r2.y, q1);
        FMA4(acc1[2], r2.z, q2); FMA4(acc1[2], r2.w, q3);
        FMA4(acc1[3], r3.x, q0); FMA4(acc1[3], r3.y, q1);
        FMA4(acc1[3], r3.z, q2); FMA4(acc1[3], r3.w, q3);
    }
    for (int k = 48; k < NG; ++k) {
        float4 q = *(const float4*)(lfw1 + k * H + c4);
        #pragma unroll
        for (int u = 0; u < 4; ++u) FMA4(acc1[u], sRbf[ub + u][k], q);
    }
    float4 b1 = *(const float4*)(fb1 + layer * H + c4);
    #pragma unroll
    for (int u = 0; u < 4; ++u) {
        float4 g;
        g.x = gelu_f(acc1[u].x + b1.x);
        g.y = gelu_f(acc1[u].y + b1.y);
        g.z = gelu_f(acc1[u].z + b1.z);
        g.w = gelu_f(acc1[u].w + b1.w);
        *(float4*)&sG[ub + u][c4] = g;
    }
    __syncthreads();

    // layer 2: sG @ fw2 (K = 256 = 64 quads)
    float4 acc2[4];
    #pragma unroll
    for (int u = 0; u < 4; ++u) acc2[u] = make_float4(0.f, 0.f, 0.f, 0.f);
    #pragma unroll 2
    for (int kq = 0; kq < 64; ++kq) {
        int k = kq * 4;
        float4 g0 = *(const float4*)&sG[ub + 0][k];
        float4 g1 = *(const float4*)&sG[ub + 1][k];
        float4 g2 = *(const float4*)&sG[ub + 2][k];
        float4 g3 = *(const float4*)&sG[ub + 3][k];
        float4 q0 = *(const float4*)(lfw2 + (k + 0) * H + c4);
        float4 q1 = *(const float4*)(lfw2 + (k + 1) * H + c4);
        float4 q2 = *(const float4*)(lfw2 + (k + 2) * H + c4);
        float4 q3 = *(const float4*)(lfw2 + (k + 3) * H + c4);
        FMA4(acc2[0], g0.x, q0); FMA4(acc2[0], g0.y, q1);
        FMA4(acc2[0], g0.z, q2); FMA4(acc2[0], g0.w, q3);
        FMA4(acc2[1], g1.x, q0); FMA4(acc2[1], g1.y, q1);
        FMA4(acc2[1], g1.z, q2); FMA4(acc2[1], g1.w, q3);
        FMA4(acc2[2], g2.x, q0); FMA4(acc2[2], g2.y, q1);
        FMA4(acc2[2], g2.z, q2); FMA4(acc2[2], g2.w, q3);
        FMA4(acc2[3], g3.x, q0); FMA4(acc2[3], g3.y, q1);
        FMA4(acc2[3], g3.z, q2); FMA4(acc2[3], g3.w, q3);
    }
    float4 b2 = *(const float4*)(fb2 + layer * H + c4);
    #pragma unroll
    for (int u = 0; u < 4; ++u) {
        int b = b0 + ub + u;
        if (b < TROWS) {
            ushort4 st;
            st.x = f2bf(acc2[u].x + b2.x);
            st.y = f2bf(acc2[u].y + b2.y);
            st.z = f2bf(acc2[u].z + b2.z);
            st.w = f2bf(acc2[u].w + b2.w);
            *(ushort4*)&lWt[(size_t)b * H + c4] = st;
        }
    }
}

// Aggregation: agg[i,c] = sum_j lerp(Wtb, d_ij)[c] * hbf[j,c] (fp32 accum).
// Block = 1 atom, 4 waves split the neighbor list. Lane owns 4 channels.
__global__ void __launch_bounds__(256) pair_k(
    const float* __restrict__ pos, const unsigned short* __restrict__ hbf,
    const unsigned short* __restrict__ Wtb, float* __restrict__ agg) {
    int tid = threadIdx.x;
    int wid = tid >> 6, lane = tid & 63;
    int c4 = lane * 4;
    int i = blockIdx.x;

    __shared__ int sCnt;
    __shared__ int sPk[N];        // j | (bin<<10)
    __shared__ float sFr[N];
    __shared__ __align__(16) float sPart[4][H];
    if (tid == 0) sCnt = 0;
    __syncthreads();

    float pix = pos[i * 3 + 0], piy = pos[i * 3 + 1], piz = pos[i * 3 + 2];
    const float invd = (float)NB / CUT;
    for (int r = 0; r < 4; ++r) {
        int j = wid * 256 + r * 64 + lane;
        float dx = pos[j * 3 + 0] - pix;
        float dy = pos[j * 3 + 1] - piy;
        float dz = pos[j * 3 + 2] - piz;
        float d = sqrtf(dx * dx + dy * dy + dz * dz);
        if (d < CUT && d > 1e-6f) {
            float u = d * invd;
            int bin = (int)u;
            if (bin > NB - 1) bin = NB - 1;
            float fr = u - (float)bin;
            int idx = atomicAdd(&sCnt, 1);
            sPk[idx] = j | (bin << 10);
            sFr[idx] = fr;
        }
    }
    __syncthreads();
    int cnt = sCnt;
    float4 acc = make_float4(0.f, 0.f, 0.f, 0.f);
    #pragma unroll 4
    for (int n = wid; n < cnt; n += 4) {
        int p = sPk[n];
        float t = sFr[n];
        int j = p & 1023;
        int bin = p >> 10;
        const unsigned short* wr = Wtb + (size_t)bin * H + c4;
        ushort4 wa = *(const ushort4*)wr;
        ushort4 wb = *(const ushort4*)(wr + H);
        ushort4 hu = *(const ushort4*)(hbf + j * H + c4);
        float ax = bf2f(wa.x), ay = bf2f(wa.y), az = bf2f(wa.z), aw = bf2f(wa.w);
        float bx = bf2f(wb.x), by = bf2f(wb.y), bz = bf2f(wb.z), bw = bf2f(wb.w);
        acc.x = fmaf(fmaf(t, bx - ax, ax), bf2f(hu.x), acc.x);
        acc.y = fmaf(fmaf(t, by - ay, ay), bf2f(hu.y), acc.y);
        acc.z = fmaf(fmaf(t, bz - az, az), bf2f(hu.z), acc.z);
        acc.w = fmaf(fmaf(t, bw - aw, aw), bf2f(hu.w), acc.w);
    }
    *(float4*)&sPart[wid][c4] = acc;
    __syncthreads();
    agg[i * H + tid] = sPart[0][tid] + sPart[1][tid] + sPart[2][tid] + sPart[3][tid];
}

// Atom MLP: hout = hin + gelu(agg@aw1+ab1)@aw2+ab2 (also emits bf16 mirror).
__global__ void __launch_bounds__(256) mlp_k(
    const float* __restrict__ agg, const float* __restrict__ hin,
    const float* __restrict__ aw1, const float* __restrict__ ab1,
    const float* __restrict__ aw2, const float* __restrict__ ab2,
    float* __restrict__ hout, unsigned short* __restrict__ hbf_out) {
    int tid = threadIdx.x;
    int wid = tid >> 6, lane = tid & 63;
    int c4 = lane * 4;
    int i0 = blockIdx.x * MATB;
    __shared__ __align__(16) float sAT[H][MATB];   // acts transposed [k][a]
    __shared__ __align__(16) float sGT[H][MATB];
    __shared__ __align__(16) float sPart[4][MATB][H];

    #pragma unroll
    for (int r = 0; r < MATB; ++r)
        sAT[tid][r] = agg[(i0 + r) * H + tid];
    __syncthreads();

    int k0 = wid * 64;
    float4 acc[MATB];
    #pragma unroll
    for (int a = 0; a < MATB; ++a) acc[a] = make_float4(0.f, 0.f, 0.f, 0.f);
    #pragma unroll 8
    for (int k = 0; k < 64; ++k) {
        float4 q = *(const float4*)(aw1 + (k0 + k) * H + c4);
        float4 act = *(const float4*)&sAT[k0 + k][0];
        FMA4(acc[0], act.x, q); FMA4(acc[1], act.y, q);
        FMA4(acc[2], act.z, q); FMA4(acc[3], act.w, q);
    }
    #pragma unroll
    for (int a = 0; a < MATB; ++a)
        *(float4*)&sPart[wid][a][c4] = acc[a];
    __syncthreads();
    {
        float b1 = ab1[tid];
        float g[MATB];
        #pragma unroll
        for (int a = 0; a < MATB; ++a) {
            float v = b1 + sPart[0][a][tid] + sPart[1][a][tid]
                         + sPart[2][a][tid] + sPart[3][a][tid];
            g[a] = gelu_f(v);
        }
        *(float4*)&sGT[tid][0] = make_float4(g[0], g[1], g[2], g[3]);
    }
    __syncthreads();
    #pragma unroll
    for (int a = 0; a < MATB; ++a) acc[a] = make_float4(0.f, 0.f, 0.f, 0.f);
    #pragma unroll 8
    for (int k = 0; k < 64; ++k) {
        float4 q = *(const float4*)(aw2 + (k0 + k) * H + c4);
        float4 act = *(const float4*)&sGT[k0 + k][0];
        FMA4(acc[0], act.x, q); FMA4(acc[1], act.y, q);
        FMA4(acc[2], act.z, q); FMA4(acc[3], act.w, q);
    }
    #pragma unroll
    for (int a = 0; a < MATB; ++a)
        *(float4*)&sPart[wid][a][c4] = acc[a];
    __syncthreads();
    {
        float b2 = ab2[tid];
        #pragma unroll
        for (int a = 0; a < MATB; ++a) {
            float v = b2 + sPart[0][a][tid] + sPart[1][a][tid]
                         + sPart[2][a][tid] + sPart[3][a][tid];
            float hv = hin[(i0 + a) * H + tid] + v;
            hout[(i0 + a) * H + tid] = hv;
            hbf_out[(i0 + a) * H + tid] = f2bf(hv);
        }
    }
}

// pooled -> gelu(pw1) -> pw2 -> layernorm. Block per molecule, waves split K.
__global__ void __launch_bounds__(256) head_k(
        const float* __restrict__ h,
        const float* __restrict__ pw1, const float* __restrict__ pb1,
        const float* __restrict__ pw2, const float* __restrict__ pb2,
        const float* __restrict__ ln_g, const float* __restrict__ ln_b,
        float* __restrict__ out) {
    int b = blockIdx.x, tid = threadIdx.x;
    int wid = tid >> 6, lane = tid & 63;
    int c4 = lane * 4;
    __shared__ float sP[H];
    __shared__ __align__(16) float sPw[4][H];
    __shared__ float sG[H];
    __shared__ __align__(16) float sP2[4][L];
    __shared__ float sX[L];
    __shared__ float sRed[256];

    float4 p = make_float4(0.f, 0.f, 0.f, 0.f);
    #pragma unroll 4
    for (int a = 0; a < 16; ++a) {
        float4 hv = *(const float4*)(h + (b * 64 + wid * 16 + a) * H + c4);
        p.x += hv.x; p.y += hv.y; p.z += hv.z; p.w += hv.w;
    }
    *(float4*)&sPw[wid][c4] = p;
    __syncthreads();
    sP[tid] = sPw[0][tid] + sPw[1][tid] + sPw[2][tid] + sPw[3][tid];
    __syncthreads();

    int k0 = wid * 64;
    float4 acc = make_float4(0.f, 0.f, 0.f, 0.f);
    #pragma unroll 8
    for (int k = 0; k < 64; ++k) {
        float4 q = *(const float4*)(pw1 + (k0 + k) * H + c4);
        float s = sP[k0 + k];
        FMA4(acc, s, q);
    }
    *(float4*)&sPw[wid][c4] = acc;
    __syncthreads();
    sG[tid] = gelu_f(pb1[tid] + sPw[0][tid] + sPw[1][tid] + sPw[2][tid] + sPw[3][tid]);
    __syncthreads();

    float4 a0 = make_float4(0.f, 0.f, 0.f, 0.f);
    float4 a1 = make_float4(0.f, 0.f, 0.f, 0.f);
    #pragma unroll 4
    for (int k = 0; k < 64; ++k) {
        float s = sG[k0 + k];
        float4 q0 = *(const float4*)(pw2 + (k0 + k) * L + lane * 8);
        float4 q1 = *(const float4*)(pw2 + (k0 + k) * L + lane * 8 + 4);
        FMA4(a0, s, q0);
        FMA4(a1, s, q1);
    }
    *(float4*)&sP2[wid][lane * 8] = a0;
    *(float4*)&sP2[wid][lane * 8 + 4] = a1;
    __syncthreads();
    for (int r = 0; r < 2; ++r) {
        int l = tid + r * 256;
        sX[l] = pb2[l] + sP2[0][l] + sP2[1][l] + sP2[2][l] + sP2[3][l];
    }
    __syncthreads();

    sRed[tid] = sX[tid] + sX[tid + 256];
    __syncthreads();
    for (int off = 128; off > 0; off >>= 1) {
        if (tid < off) sRed[tid] += sRed[tid + off];
        __syncthreads();
    }
    float mu = sRed[0] / (float)L;
    __syncthreads();
    float d0 = sX[tid] - mu, d1 = sX[tid + 256] - mu;
    sRed[tid] = d0 * d0 + d1 * d1;
    __syncthreads();
    for (int off = 128; off > 0; off >>= 1) {
        if (tid < off) sRed[tid] += sRed[tid + off];
        __syncthreads();
    }
    float var = sRed[0] / (float)L;
    float rstd = rsqrtf(var + 1e-5f);
    for (int r = 0; r < 2; ++r) {
        int l = tid + r * 256;
        out[b * L + l] = (sX[l] - mu) * rstd * ln_g[l] + ln_b[l];
    }
}

extern "C" void kernel_launch(void* const* d_in, const int* in_sizes, int n_in,
                              void* d_out, int out_size, void* d_ws, size_t ws_size,
                              hipStream_t stream) {
    const int*   z    = (const int*)d_in[0];
    const float* pos  = (const float*)d_in[1];
    // d_in[2] = batch: fixed arange//64 layout, handled implicitly in head_k
    const float* emb  = (const float*)d_in[3];
    const float* fw1  = (const float*)d_in[4];
    const float* fb1  = (const float*)d_in[5];
    const float* fw2  = (const float*)d_in[6];
    const float* fb2  = (const float*)d_in[7];
    const float* aw1  = (const float*)d_in[8];
    const float* ab1  = (const float*)d_in[9];
    const float* aw2  = (const float*)d_in[10];
    const float* ab2  = (const float*)d_in[11];
    const float* pw1  = (const float*)d_in[12];
    const float* pb1  = (const float*)d_in[13];
    const float* pw2  = (const float*)d_in[14];
    const float* pb2  = (const float*)d_in[15];
    const float* ln_g = (const float*)d_in[16];
    const float* ln_b = (const float*)d_in[17];
    float* out = (float*)d_out;

    float* hA  = (float*)d_ws;                        // [N][H] fp32
    float* hB  = hA + N * H;                          // [N][H] fp32
    float* agg = hB + N * H;                          // [N][H] fp32
    unsigned short* hbfA = (unsigned short*)(agg + N * H);   // [N][H] bf16
    unsigned short* hbfB = hbfA + N * H;                     // [N][H] bf16
    unsigned short* Wtb  = hbfB + N * H;              // [NI][TROWS][H] bf16

    embed_k<<<N, H, 0, stream>>>(z, emb, hA, hbfA);
    {
        int bpl = (TROWS + BPB - 1) / BPB;
        table_k<<<NI * bpl, 256, 0, stream>>>(fw1, fb1, fw2, fb2, Wtb);
    }
    float* hin = hA;  unsigned short* hbin = hbfA;
    float* hout = hB; unsigned short* hbout = hbfB;
    for (int it = 0; it < NI; ++it) {
        pair_k<<<N, 256, 0, stream>>>(pos, hbin, Wtb + (size_t)it * TROWS * H, agg);
        mlp_k<<<N / MATB, 256, 0, stream>>>(agg, hin, aw1 + it * H * H, ab1 + it * H,
                                            aw2 + it * H * H, ab2 + it * H, hout, hbout);
        float* t1 = hin; hin = hout; hout = t1;
        unsigned short* t2 = hbin; hbin = hbout; hbout = t2;
    }
    head_k<<<B, 256, 0, stream>>>(hin, pw1, pb1, pw2, pb2, ln_g, ln_b, out);
}

// Round 6
// 295.178 us; speedup vs baseline: 1.7882x; 1.0230x over previous
//
#include <hip/hip_runtime.h>
#include <math.h>

#define N 1024
#define H 256
#define L 512
#define NG 50
#define NI 3
#define B 16
#define NB 2048            // distance-LUT bins over [0, CUT]
#define CUT 5.0f
#define BPB 16             // bins per block in table_k (4 per wave)
#define TROWS (NB + 1)     // 2049 rows per table (bf16 scalar table)
#define PROWS (NB + 1)     // packed-pair table rows: 0..NB-1 pairs, NB = zero sentinel
#define MATB 4             // atoms per block in mlp_k

// NOTE: param must NOT be named 'w' — it would capture the '.w' member token.
#define FMA4(A_, S_, V_) do { \
    (A_).x = fmaf((S_), (V_).x, (A_).x); (A_).y = fmaf((S_), (V_).y, (A_).y); \
    (A_).z = fmaf((S_), (V_).z, (A_).z); (A_).w = fmaf((S_), (V_).w, (A_).w); } while (0)

__device__ __forceinline__ float gelu_f(float x) {
    return 0.5f * x * (1.0f + erff(x * 0.70710678118654752f));
}
__device__ __forceinline__ unsigned short f2bf(float f) {
    unsigned u = __float_as_uint(f);
    unsigned r = (u + 0x7fffu + ((u >> 16) & 1u)) >> 16;   // RNE
    return (unsigned short)r;
}
__device__ __forceinline__ float bf_lo(unsigned u) {       // low bf16 -> f32
    return __uint_as_float(u << 16);
}
__device__ __forceinline__ float bf_hi(unsigned u) {       // high bf16 -> f32
    return __uint_as_float(u & 0xffff0000u);
}

__global__ void embed_k(const int* __restrict__ z, const float* __restrict__ emb,
                        float* __restrict__ h, unsigned short* __restrict__ hbf) {
    int i = blockIdx.x, c = threadIdx.x;
    float v = emb[z[i] * H + c];
    h[i * H + c] = v;
    hbf[i * H + c] = f2bf(v);
}

// Build all NI tables (bf16 output). grid = NI * ceil(TROWS/BPB) = 3*129.
__global__ void __launch_bounds__(256) table_k(
        const float* __restrict__ fw1, const float* __restrict__ fb1,
        const float* __restrict__ fw2, const float* __restrict__ fb2,
        unsigned short* __restrict__ Wtb) {
    const int bpl = (TROWS + BPB - 1) / BPB;      // 129 blocks per layer
    int layer = blockIdx.x / bpl;
    int blk = blockIdx.x % bpl;
    int b0 = blk * BPB;
    int tid = threadIdx.x;
    int wid = tid >> 6, lane = tid & 63;
    int c4 = lane * 4;
    int ub = wid * 4;                             // wave's first bin slot
    const float* lfw1 = fw1 + layer * NG * H;
    const float* lfw2 = fw2 + layer * H * H;
    unsigned short* lWt = Wtb + (size_t)layer * TROWS * H;

    __shared__ __align__(16) float sRbf[BPB][56];  // 56: 16B-aligned rows
    __shared__ __align__(16) float sG[BPB][H];
    const float delta = CUT / (float)NB;
    for (int idx = tid; idx < BPB * NG; idx += 256) {
        int u = idx & 15;
        int k = idx >> 4;
        float d = (float)(b0 + u) * delta;
        float t = d - (float)k * (CUT / 49.0f);   // centers = linspace(0,5,50)
        sRbf[u][k] = expf(t * t * -200.0f);       // -1/(2*0.05^2)
    }
    __syncthreads();

    // layer 1: rbf @ fw1 (K = 50 = 12 quads + 2)
    float4 acc1[4];
    #pragma unroll
    for (int u = 0; u < 4; ++u) acc1[u] = make_float4(0.f, 0.f, 0.f, 0.f);
    for (int kq = 0; kq < 12; ++kq) {
        int k = kq * 4;
        float4 r0 = *(const float4*)&sRbf[ub + 0][k];
        float4 r1 = *(const float4*)&sRbf[ub + 1][k];
        float4 r2 = *(const float4*)&sRbf[ub + 2][k];
        float4 r3 = *(const float4*)&sRbf[ub + 3][k];
        float4 q0 = *(const float4*)(lfw1 + (k + 0) * H + c4);
        float4 q1 = *(const float4*)(lfw1 + (k + 1) * H + c4);
        float4 q2 = *(const float4*)(lfw1 + (k + 2) * H + c4);
        float4 q3 = *(const float4*)(lfw1 + (k + 3) * H + c4);
        FMA4(acc1[0], r0.x, q0); FMA4(acc1[0], r0.y, q1);
        FMA4(acc1[0], r0.z, q2); FMA4(acc1[0], r0.w, q3);
        FMA4(acc1[1], r1.x, q0); FMA4(acc1[1], r1.y, q1);
        FMA4(acc1[1], r1.z, q2); FMA4(acc1[1], r1.w, q3);
        FMA4(acc1[2], r2.x, q0); FMA4(acc1[2], r2.y, q1);
        FMA4(acc1[2], r2.z, q2); FMA4(acc1[2], r2.w, q3);
        FMA4(acc1[3], r3.x, q0); FMA4(acc1[3], r3.y, q1);
        FMA4(acc1[3], r3.z, q2); FMA4(acc1[3], r3.w, q3);
    }
    for (int k = 48; k < NG; ++k) {
        float4 q = *(const float4*)(lfw1 + k * H + c4);
        #pragma unroll
        for (int u = 0; u < 4; ++u) FMA4(acc1[u], sRbf[ub + u][k], q);
    }
    float4 b1 = *(const float4*)(fb1 + layer * H + c4);
    #pragma unroll
    for (int u = 0; u < 4; ++u) {
        float4 g;
        g.x = gelu_f(acc1[u].x + b1.x);
        g.y = gelu_f(acc1[u].y + b1.y);
        g.z = gelu_f(acc1[u].z + b1.z);
        g.w = gelu_f(acc1[u].w + b1.w);
        *(float4*)&sG[ub + u][c4] = g;
    }
    __syncthreads();

    // layer 2: sG @ fw2 (K = 256 = 64 quads)
    float4 acc2[4];
    #pragma unroll
    for (int u = 0; u < 4; ++u) acc2[u] = make_float4(0.f, 0.f, 0.f, 0.f);
    for (int kq = 0; kq < 64; ++kq) {
        int k = kq * 4;
        float4 g0 = *(const float4*)&sG[ub + 0][k];
        float4 g1 = *(const float4*)&sG[ub + 1][k];
        float4 g2 = *(const float4*)&sG[ub + 2][k];
        float4 g3 = *(const float4*)&sG[ub + 3][k];
        float4 q0 = *(const float4*)(lfw2 + (k + 0) * H + c4);
        float4 q1 = *(const float4*)(lfw2 + (k + 1) * H + c4);
        float4 q2 = *(const float4*)(lfw2 + (k + 2) * H + c4);
        float4 q3 = *(const float4*)(lfw2 + (k + 3) * H + c4);
        FMA4(acc2[0], g0.x, q0); FMA4(acc2[0], g0.y, q1);
        FMA4(acc2[0], g0.z, q2); FMA4(acc2[0], g0.w, q3);
        FMA4(acc2[1], g1.x, q0); FMA4(acc2[1], g1.y, q1);
        FMA4(acc2[1], g1.z, q2); FMA4(acc2[1], g1.w, q3);
        FMA4(acc2[2], g2.x, q0); FMA4(acc2[2], g2.y, q1);
        FMA4(acc2[2], g2.z, q2); FMA4(acc2[2], g2.w, q3);
        FMA4(acc2[3], g3.x, q0); FMA4(acc2[3], g3.y, q1);
        FMA4(acc2[3], g3.z, q2); FMA4(acc2[3], g3.w, q3);
    }
    float4 b2 = *(const float4*)(fb2 + layer * H + c4);
    #pragma unroll
    for (int u = 0; u < 4; ++u) {
        int b = b0 + ub + u;
        if (b < TROWS) {
            ushort4 st;
            st.x = f2bf(acc2[u].x + b2.x);
            st.y = f2bf(acc2[u].y + b2.y);
            st.z = f2bf(acc2[u].z + b2.z);
            st.w = f2bf(acc2[u].w + b2.w);
            *(ushort4*)&lWt[(size_t)b * H + c4] = st;
        }
    }
}

// Pack lerp row pairs: Wp[l][b][c] = Wt[l][b][c] | (Wt[l][b+1][c] << 16).
// Row b == NB is the zero sentinel (used by padded neighbor slots).
__global__ void pack_k(const unsigned short* __restrict__ Wt,
                       unsigned* __restrict__ Wp) {
    int row = blockIdx.x;                  // 0 .. NI*PROWS-1
    int l = row / PROWS;
    int b = row % PROWS;
    const unsigned short* src = Wt + ((size_t)l * TROWS + b) * H;
    unsigned* dst = Wp + ((size_t)l * PROWS + b) * H;
    int c = threadIdx.x;
    unsigned v = 0;
    if (b < NB) v = (unsigned)src[c] | ((unsigned)src[c + H] << 16);
    dst[c] = v;
}

// Aggregation: agg[i,c] = sum_j lerp(W, d_ij)[c] * h[j,c] (fp32 accum).
// Block = 1 atom, 4 waves split the (padded) neighbor list; lane owns 4
// channels. Inner loop: double-buffered 4-neighbor chunks, 16 loads in flight.
__global__ void __launch_bounds__(256) pair_k(
    const float* __restrict__ pos, const unsigned short* __restrict__ hbf,
    const unsigned* __restrict__ Wp, float* __restrict__ agg) {
    int tid = threadIdx.x;
    int wid = tid >> 6, lane = tid & 63;
    int c4 = lane * 4;
    int i = blockIdx.x;

    __shared__ int sCnt;
    __shared__ __align__(8) float2 sMeta[N + 32];   // {as_float(j|bin<<10), fr}
    __shared__ __align__(16) float sPart[4][H];
    if (tid == 0) sCnt = 0;
    __syncthreads();

    float pix = pos[i * 3 + 0], piy = pos[i * 3 + 1], piz = pos[i * 3 + 2];
    const float invd = (float)NB / CUT;
    for (int r = 0; r < 4; ++r) {
        int j = wid * 256 + r * 64 + lane;
        float dx = pos[j * 3 + 0] - pix;
        float dy = pos[j * 3 + 1] - piy;
        float dz = pos[j * 3 + 2] - piz;
        float d = sqrtf(dx * dx + dy * dy + dz * dz);
        if (d < CUT && d > 1e-6f) {
            float u = d * invd;
            int bin = (int)u;
            if (bin > NB - 1) bin = NB - 1;
            float fr = u - (float)bin;
            int idx = atomicAdd(&sCnt, 1);
            sMeta[idx] = make_float2(__int_as_float(j | (bin << 10)), fr);
        }
    }
    __syncthreads();
    int cnt = sCnt;
    int pc = (cnt + 31) & ~31;            // pad to x32 -> even chunk count
    // sentinel: bin NB -> zero row in Wp, contribution exactly 0
    for (int t = cnt + tid; t < pc; t += 256)
        sMeta[t] = make_float2(__int_as_float(i | (NB << 10)), 0.f);
    __syncthreads();

    float4 acc = make_float4(0.f, 0.f, 0.f, 0.f);
    int chunks = pc >> 4;                 // chunks per wave (4 neighbors each)

    uint4 wA[4], wB[4];
    uint2 hA[4], hB[4];
    float tA[4], tB[4];

    auto issue = [&](int q, uint4 (&wr)[4], uint2 (&hr)[4], float (&tr)[4]) {
        #pragma unroll
        for (int s = 0; s < 4; ++s) {
            int n = wid + (q * 4 + s) * 4;        // wave-uniform -> LDS broadcast
            float2 mt = sMeta[n];
            int pk = __float_as_int(mt.x);
            tr[s] = mt.y;
            int j = pk & 1023;
            int bin = pk >> 10;
            wr[s] = *(const uint4*)(Wp + bin * H + c4);
            hr[s] = *(const uint2*)(hbf + j * H + c4);
        }
    };
    auto consume = [&](uint4 (&wr)[4], uint2 (&hr)[4], float (&tr)[4]) {
        #pragma unroll
        for (int s = 0; s < 4; ++s) {
            float t = tr[s];
            float w0, w1, hv;
            w0 = bf_lo(wr[s].x); w1 = bf_hi(wr[s].x); hv = bf_lo(hr[s].x);
            acc.x = fmaf(fmaf(t, w1 - w0, w0), hv, acc.x);
            w0 = bf_lo(wr[s].y); w1 = bf_hi(wr[s].y); hv = bf_hi(hr[s].x);
            acc.y = fmaf(fmaf(t, w1 - w0, w0), hv, acc.y);
            w0 = bf_lo(wr[s].z); w1 = bf_hi(wr[s].z); hv = bf_lo(hr[s].y);
            acc.z = fmaf(fmaf(t, w1 - w0, w0), hv, acc.z);
            w0 = bf_lo(wr[s].w); w1 = bf_hi(wr[s].w); hv = bf_hi(hr[s].y);
            acc.w = fmaf(fmaf(t, w1 - w0, w0), hv, acc.w);
        }
    };

    if (chunks > 0) {
        issue(0, wA, hA, tA);
        issue(1, wB, hB, tB);
        for (int q = 0; q < chunks; q += 2) {
            consume(wA, hA, tA);
            if (q + 2 < chunks) issue(q + 2, wA, hA, tA);
            consume(wB, hB, tB);
            if (q + 3 < chunks) issue(q + 3, wB, hB, tB);
        }
    }
    *(float4*)&sPart[wid][c4] = acc;
    __syncthreads();
    agg[i * H + tid] = sPart[0][tid] + sPart[1][tid] + sPart[2][tid] + sPart[3][tid];
}

// Atom MLP: hout = hin + gelu(agg@aw1+ab1)@aw2+ab2 (also emits bf16 mirror).
__global__ void __launch_bounds__(256) mlp_k(
    const float* __restrict__ agg, const float* __restrict__ hin,
    const float* __restrict__ aw1, const float* __restrict__ ab1,
    const float* __restrict__ aw2, const float* __restrict__ ab2,
    float* __restrict__ hout, unsigned short* __restrict__ hbf_out) {
    int tid = threadIdx.x;
    int wid = tid >> 6, lane = tid & 63;
    int c4 = lane * 4;
    int i0 = blockIdx.x * MATB;
    __shared__ __align__(16) float sAT[H][MATB];   // acts transposed [k][a]
    __shared__ __align__(16) float sGT[H][MATB];
    __shared__ __align__(16) float sPart[4][MATB][H];

    #pragma unroll
    for (int r = 0; r < MATB; ++r)
        sAT[tid][r] = agg[(i0 + r) * H + tid];
    __syncthreads();

    int k0 = wid * 64;
    float4 acc[MATB];
    #pragma unroll
    for (int a = 0; a < MATB; ++a) acc[a] = make_float4(0.f, 0.f, 0.f, 0.f);
    #pragma unroll 8
    for (int k = 0; k < 64; ++k) {
        float4 q = *(const float4*)(aw1 + (k0 + k) * H + c4);
        float4 act = *(const float4*)&sAT[k0 + k][0];
        FMA4(acc[0], act.x, q); FMA4(acc[1], act.y, q);
        FMA4(acc[2], act.z, q); FMA4(acc[3], act.w, q);
    }
    #pragma unroll
    for (int a = 0; a < MATB; ++a)
        *(float4*)&sPart[wid][a][c4] = acc[a];
    __syncthreads();
    {
        float b1 = ab1[tid];
        float g[MATB];
        #pragma unroll
        for (int a = 0; a < MATB; ++a) {
            float v = b1 + sPart[0][a][tid] + sPart[1][a][tid]
                         + sPart[2][a][tid] + sPart[3][a][tid];
            g[a] = gelu_f(v);
        }
        *(float4*)&sGT[tid][0] = make_float4(g[0], g[1], g[2], g[3]);
    }
    __syncthreads();
    #pragma unroll
    for (int a = 0; a < MATB; ++a) acc[a] = make_float4(0.f, 0.f, 0.f, 0.f);
    #pragma unroll 8
    for (int k = 0; k < 64; ++k) {
        float4 q = *(const float4*)(aw2 + (k0 + k) * H + c4);
        float4 act = *(const float4*)&sGT[k0 + k][0];
        FMA4(acc[0], act.x, q); FMA4(acc[1], act.y, q);
        FMA4(acc[2], act.z, q); FMA4(acc[3], act.w, q);
    }
    #pragma unroll
    for (int a = 0; a < MATB; ++a)
        *(float4*)&sPart[wid][a][c4] = acc[a];
    __syncthreads();
    {
        float b2 = ab2[tid];
        #pragma unroll
        for (int a = 0; a < MATB; ++a) {
            float v = b2 + sPart[0][a][tid] + sPart[1][a][tid]
                         + sPart[2][a][tid] + sPart[3][a][tid];
            float hv = hin[(i0 + a) * H + tid] + v;
            hout[(i0 + a) * H + tid] = hv;
            hbf_out[(i0 + a) * H + tid] = f2bf(hv);
        }
    }
}

// pooled -> gelu(pw1) -> pw2 -> layernorm. Block per molecule, waves split K.
__global__ void __launch_bounds__(256) head_k(
        const float* __restrict__ h,
        const float* __restrict__ pw1, const float* __restrict__ pb1,
        const float* __restrict__ pw2, const float* __restrict__ pb2,
        const float* __restrict__ ln_g, const float* __restrict__ ln_b,
        float* __restrict__ out) {
    int b = blockIdx.x, tid = threadIdx.x;
    int wid = tid >> 6, lane = tid & 63;
    int c4 = lane * 4;
    __shared__ float sP[H];
    __shared__ __align__(16) float sPw[4][H];
    __shared__ float sG[H];
    __shared__ __align__(16) float sP2[4][L];
    __shared__ float sX[L];
    __shared__ float sRed[256];

    float4 p = make_float4(0.f, 0.f, 0.f, 0.f);
    #pragma unroll 4
    for (int a = 0; a < 16; ++a) {
        float4 hv = *(const float4*)(h + (b * 64 + wid * 16 + a) * H + c4);
        p.x += hv.x; p.y += hv.y; p.z += hv.z; p.w += hv.w;
    }
    *(float4*)&sPw[wid][c4] = p;
    __syncthreads();
    sP[tid] = sPw[0][tid] + sPw[1][tid] + sPw[2][tid] + sPw[3][tid];
    __syncthreads();

    int k0 = wid * 64;
    float4 acc = make_float4(0.f, 0.f, 0.f, 0.f);
    #pragma unroll 8
    for (int k = 0; k < 64; ++k) {
        float4 q = *(const float4*)(pw1 + (k0 + k) * H + c4);
        float s = sP[k0 + k];
        FMA4(acc, s, q);
    }
    *(float4*)&sPw[wid][c4] = acc;
    __syncthreads();
    sG[tid] = gelu_f(pb1[tid] + sPw[0][tid] + sPw[1][tid] + sPw[2][tid] + sPw[3][tid]);
    __syncthreads();

    float4 a0 = make_float4(0.f, 0.f, 0.f, 0.f);
    float4 a1 = make_float4(0.f, 0.f, 0.f, 0.f);
    #pragma unroll 4
    for (int k = 0; k < 64; ++k) {
        float s = sG[k0 + k];
        float4 q0 = *(const float4*)(pw2 + (k0 + k) * L + lane * 8);
        float4 q1 = *(const float4*)(pw2 + (k0 + k) * L + lane * 8 + 4);
        FMA4(a0, s, q0);
        FMA4(a1, s, q1);
    }
    *(float4*)&sP2[wid][lane * 8] = a0;
    *(float4*)&sP2[wid][lane * 8 + 4] = a1;
    __syncthreads();
    for (int r = 0; r < 2; ++r) {
        int l = tid + r * 256;
        sX[l] = pb2[l] + sP2[0][l] + sP2[1][l] + sP2[2][l] + sP2[3][l];
    }
    __syncthreads();

    sRed[tid] = sX[tid] + sX[tid + 256];
    __syncthreads();
    for (int off = 128; off > 0; off >>= 1) {
        if (tid < off) sRed[tid] += sRed[tid + off];
        __syncthreads();
    }
    float mu = sRed[0] / (float)L;
    __syncthreads();
    float d0 = sX[tid] - mu, d1 = sX[tid + 256] - mu;
    sRed[tid] = d0 * d0 + d1 * d1;
    __syncthreads();
    for (int off = 128; off > 0; off >>= 1) {
        if (tid < off) sRed[tid] += sRed[tid + off];
        __syncthreads();
    }
    float var = sRed[0] / (float)L;
    float rstd = rsqrtf(var + 1e-5f);
    for (int r = 0; r < 2; ++r) {
        int l = tid + r * 256;
        out[b * L + l] = (sX[l] - mu) * rstd * ln_g[l] + ln_b[l];
    }
}

extern "C" void kernel_launch(void* const* d_in, const int* in_sizes, int n_in,
                              void* d_out, int out_size, void* d_ws, size_t ws_size,
                              hipStream_t stream) {
    const int*   z    = (const int*)d_in[0];
    const float* pos  = (const float*)d_in[1];
    // d_in[2] = batch: fixed arange//64 layout, handled implicitly in head_k
    const float* emb  = (const float*)d_in[3];
    const float* fw1  = (const float*)d_in[4];
    const float* fb1  = (const float*)d_in[5];
    const float* fw2  = (const float*)d_in[6];
    const float* fb2  = (const float*)d_in[7];
    const float* aw1  = (const float*)d_in[8];
    const float* ab1  = (const float*)d_in[9];
    const float* aw2  = (const float*)d_in[10];
    const float* ab2  = (const float*)d_in[11];
    const float* pw1  = (const float*)d_in[12];
    const float* pb1  = (const float*)d_in[13];
    const float* pw2  = (const float*)d_in[14];
    const float* pb2  = (const float*)d_in[15];
    const float* ln_g = (const float*)d_in[16];
    const float* ln_b = (const float*)d_in[17];
    float* out = (float*)d_out;

    float* hA  = (float*)d_ws;                        // [N][H] fp32
    float* hB  = hA + N * H;                          // [N][H] fp32
    float* agg = hB + N * H;                          // [N][H] fp32
    unsigned short* hbfA = (unsigned short*)(agg + N * H);   // [N][H] bf16
    unsigned short* hbfB = hbfA + N * H;                     // [N][H] bf16
    unsigned short* Wtb  = hbfB + N * H;              // [NI][TROWS][H] bf16
    unsigned* Wp = (unsigned*)(Wtb + (size_t)NI * TROWS * H); // [NI][PROWS][H] packed

    embed_k<<<N, H, 0, stream>>>(z, emb, hA, hbfA);
    {
        int bpl = (TROWS + BPB - 1) / BPB;
        table_k<<<NI * bpl, 256, 0, stream>>>(fw1, fb1, fw2, fb2, Wtb);
        pack_k<<<NI * PROWS, 256, 0, stream>>>(Wtb, Wp);
    }
    float* hin = hA;  unsigned short* hbin = hbfA;
    float* hout = hB; unsigned short* hbout = hbfB;
    for (int it = 0; it < NI; ++it) {
        pair_k<<<N, 256, 0, stream>>>(pos, hbin, Wp + (size_t)it * PROWS * H, agg);
        mlp_k<<<N / MATB, 256, 0, stream>>>(agg, hin, aw1 + it * H * H, ab1 + it * H,
                                            aw2 + it * H * H, ab2 + it * H, hout, hbout);
        float* t1 = hin; hin = hout; hout = t1;
        unsigned short* t2 = hbin; hbin = hbout; hbout = t2;
    }
    head_k<<<B, 256, 0, stream>>>(hin, pw1, pb1, pw2, pb2, ln_g, ln_b, out);
}

// Round 7
// 281.348 us; speedup vs baseline: 1.8761x; 1.0492x over previous
//
#include <hip/hip_runtime.h>
#include <math.h>

#define N 1024
#define H 256
#define L 512
#define NG 50
#define NI 3
#define B 16
#define NB 2048            // distance-LUT bins over [0, CUT]
#define CUT 5.0f
#define BPB 16             // bins per block in table_k (4 per wave)
#define TROWS (NB + 1)     // 2049 rows per table (bf16 scalar table)
#define PROWS (NB + 1)     // packed-pair rows: 0..NB-1 pairs, NB = zero sentinel
#define MATB 4             // atoms per block in mlp_k
#define CAP 768            // max (padded) neighbors per atom

// NOTE: param must NOT be named 'w' — it would capture the '.w' member token.
#define FMA4(A_, S_, V_) do { \
    (A_).x = fmaf((S_), (V_).x, (A_).x); (A_).y = fmaf((S_), (V_).y, (A_).y); \
    (A_).z = fmaf((S_), (V_).z, (A_).z); (A_).w = fmaf((S_), (V_).w, (A_).w); } while (0)

__device__ __forceinline__ float gelu_f(float x) {
    return 0.5f * x * (1.0f + erff(x * 0.70710678118654752f));
}
__device__ __forceinline__ unsigned short f2bf(float f) {
    unsigned u = __float_as_uint(f);
    unsigned r = (u + 0x7fffu + ((u >> 16) & 1u)) >> 16;   // RNE
    return (unsigned short)r;
}
__device__ __forceinline__ float bf_lo(unsigned u) { return __uint_as_float(u << 16); }
__device__ __forceinline__ float bf_hi(unsigned u) { return __uint_as_float(u & 0xffff0000u); }

__global__ void embed_k(const int* __restrict__ z, const float* __restrict__ emb,
                        float* __restrict__ h, unsigned short* __restrict__ hbf) {
    int i = blockIdx.x, c = threadIdx.x;
    float v = emb[z[i] * H + c];
    h[i * H + c] = v;
    hbf[i * H + c] = f2bf(v);
}

// Build neighbor lists ONCE (identical for all NI iterations).
// meta[i][t] = {as_float(j | bin<<10), fr}; padded to x32 with zero-row sentinel.
__global__ void __launch_bounds__(256) nbrbuild_k(
        const float* __restrict__ pos, float2* __restrict__ meta,
        int* __restrict__ cnts) {
    int i = blockIdx.x;
    int tid = threadIdx.x;
    __shared__ int sCnt;
    __shared__ __align__(8) float2 sMeta[CAP];
    if (tid == 0) sCnt = 0;
    __syncthreads();
    float pix = pos[i * 3 + 0], piy = pos[i * 3 + 1], piz = pos[i * 3 + 2];
    const float invd = (float)NB / CUT;
    for (int r = 0; r < 4; ++r) {
        int j = tid + r * 256;
        float dx = pos[j * 3 + 0] - pix;
        float dy = pos[j * 3 + 1] - piy;
        float dz = pos[j * 3 + 2] - piz;
        float d = sqrtf(dx * dx + dy * dy + dz * dz);
        if (d < CUT && d > 1e-6f) {
            float u = d * invd;
            int bin = (int)u;
            if (bin > NB - 1) bin = NB - 1;
            float fr = u - (float)bin;
            int idx = atomicAdd(&sCnt, 1);
            sMeta[idx] = make_float2(__int_as_float(j | (bin << 10)), fr);
        }
    }
    __syncthreads();
    int cnt = sCnt;
    int pc = (cnt + 31) & ~31;
    for (int t = cnt + tid; t < pc; t += 256)
        sMeta[t] = make_float2(__int_as_float(i | (NB << 10)), 0.f);  // zero row
    __syncthreads();
    for (int t = tid; t < pc; t += 256)
        meta[(size_t)i * CAP + t] = sMeta[t];
    if (tid == 0) cnts[i] = pc;
}

// Build all NI tables (bf16 output). grid = NI * 129. fw2 staged in LDS tiles.
__global__ void __launch_bounds__(256) table_k(
        const float* __restrict__ fw1, const float* __restrict__ fb1,
        const float* __restrict__ fw2, const float* __restrict__ fb2,
        unsigned short* __restrict__ Wtb) {
    const int bpl = (TROWS + BPB - 1) / BPB;      // 129 blocks per layer
    int layer = blockIdx.x / bpl;
    int blk = blockIdx.x % bpl;
    int b0 = blk * BPB;
    int tid = threadIdx.x;
    int wid = tid >> 6, lane = tid & 63;
    int c4 = lane * 4;
    int ub = wid * 4;                             // wave's first bin slot
    const float* lfw1 = fw1 + layer * NG * H;
    const float* lfw2 = fw2 + layer * H * H;
    unsigned short* lWt = Wtb + (size_t)layer * TROWS * H;

    __shared__ __align__(16) float sRbf[BPB][56];
    __shared__ __align__(16) float sG[BPB][H];    // 16 KB
    __shared__ __align__(16) float sW[32][H];     // 32 KB fw2 tile
    const float delta = CUT / (float)NB;
    for (int idx = tid; idx < BPB * NG; idx += 256) {
        int u = idx & 15;
        int k = idx >> 4;
        float d = (float)(b0 + u) * delta;
        float t = d - (float)k * (CUT / 49.0f);   // centers = linspace(0,5,50)
        sRbf[u][k] = expf(t * t * -200.0f);       // -1/(2*0.05^2)
    }
    __syncthreads();

    // layer 1: rbf @ fw1 (K = 50 = 12 quads + 2)
    float4 acc1[4];
    #pragma unroll
    for (int u = 0; u < 4; ++u) acc1[u] = make_float4(0.f, 0.f, 0.f, 0.f);
    for (int kq = 0; kq < 12; ++kq) {
        int k = kq * 4;
        float4 r0 = *(const float4*)&sRbf[ub + 0][k];
        float4 r1 = *(const float4*)&sRbf[ub + 1][k];
        float4 r2 = *(const float4*)&sRbf[ub + 2][k];
        float4 r3 = *(const float4*)&sRbf[ub + 3][k];
        float4 q0 = *(const float4*)(lfw1 + (k + 0) * H + c4);
        float4 q1 = *(const float4*)(lfw1 + (k + 1) * H + c4);
        float4 q2 = *(const float4*)(lfw1 + (k + 2) * H + c4);
        float4 q3 = *(const float4*)(lfw1 + (k + 3) * H + c4);
        FMA4(acc1[0], r0.x, q0); FMA4(acc1[0], r0.y, q1);
        FMA4(acc1[0], r0.z, q2); FMA4(acc1[0], r0.w, q3);
        FMA4(acc1[1], r1.x, q0); FMA4(acc1[1], r1.y, q1);
        FMA4(acc1[1], r1.z, q2); FMA4(acc1[1], r1.w, q3);
        FMA4(acc1[2], r2.x, q0); FMA4(acc1[2], r2.y, q1);
        FMA4(acc1[2], r2.z, q2); FMA4(acc1[2], r2.w, q3);
        FMA4(acc1[3], r3.x, q0); FMA4(acc1[3], r3.y, q1);
        FMA4(acc1[3], r3.z, q2); FMA4(acc1[3], r3.w, q3);
    }
    for (int k = 48; k < NG; ++k) {
        float4 q = *(const float4*)(lfw1 + k * H + c4);
        #pragma unroll
        for (int u = 0; u < 4; ++u) FMA4(acc1[u], sRbf[ub + u][k], q);
    }
    float4 b1 = *(const float4*)(fb1 + layer * H + c4);
    #pragma unroll
    for (int u = 0; u < 4; ++u) {
        float4 g;
        g.x = gelu_f(acc1[u].x + b1.x);
        g.y = gelu_f(acc1[u].y + b1.y);
        g.z = gelu_f(acc1[u].z + b1.z);
        g.w = gelu_f(acc1[u].w + b1.w);
        *(float4*)&sG[ub + u][c4] = g;
    }
    __syncthreads();

    // layer 2: sG @ fw2, fw2 staged in 32-row LDS tiles (8 tiles)
    float4 acc2[4];
    #pragma unroll
    for (int u = 0; u < 4; ++u) acc2[u] = make_float4(0.f, 0.f, 0.f, 0.f);
    for (int t = 0; t < 8; ++t) {
        const float* src = lfw2 + (size_t)(t * 32) * H;
        #pragma unroll
        for (int p = 0; p < 8; ++p) {
            int idx = tid + p * 256;              // float4 index 0..2047
            int row = idx >> 6;
            int col4 = (idx & 63) * 4;
            *(float4*)&sW[row][col4] = *(const float4*)(src + row * H + col4);
        }
        __syncthreads();
        for (int kq = 0; kq < 8; ++kq) {
            int k = t * 32 + kq * 4;              // global k (sG column)
            int kl = kq * 4;                      // local row in sW
            float4 g0 = *(const float4*)&sG[ub + 0][k];
            float4 g1 = *(const float4*)&sG[ub + 1][k];
            float4 g2 = *(const float4*)&sG[ub + 2][k];
            float4 g3 = *(const float4*)&sG[ub + 3][k];
            float4 q0 = *(const float4*)&sW[kl + 0][c4];
            float4 q1 = *(const float4*)&sW[kl + 1][c4];
            float4 q2 = *(const float4*)&sW[kl + 2][c4];
            float4 q3 = *(const float4*)&sW[kl + 3][c4];
            FMA4(acc2[0], g0.x, q0); FMA4(acc2[0], g0.y, q1);
            FMA4(acc2[0], g0.z, q2); FMA4(acc2[0], g0.w, q3);
            FMA4(acc2[1], g1.x, q0); FMA4(acc2[1], g1.y, q1);
            FMA4(acc2[1], g1.z, q2); FMA4(acc2[1], g1.w, q3);
            FMA4(acc2[2], g2.x, q0); FMA4(acc2[2], g2.y, q1);
            FMA4(acc2[2], g2.z, q2); FMA4(acc2[2], g2.w, q3);
            FMA4(acc2[3], g3.x, q0); FMA4(acc2[3], g3.y, q1);
            FMA4(acc2[3], g3.z, q2); FMA4(acc2[3], g3.w, q3);
        }
        __syncthreads();
    }
    float4 b2 = *(const float4*)(fb2 + layer * H + c4);
    #pragma unroll
    for (int u = 0; u < 4; ++u) {
        int b = b0 + ub + u;
        if (b < TROWS) {
            ushort4 st;
            st.x = f2bf(acc2[u].x + b2.x);
            st.y = f2bf(acc2[u].y + b2.y);
            st.z = f2bf(acc2[u].z + b2.z);
            st.w = f2bf(acc2[u].w + b2.w);
            *(ushort4*)&lWt[(size_t)b * H + c4] = st;
        }
    }
}

// Pack lerp row pairs: Wp[l][b][c] = Wt[l][b][c] | (Wt[l][b+1][c] << 16).
// Row b == NB is the zero sentinel (used by padded neighbor slots).
__global__ void pack_k(const unsigned short* __restrict__ Wt,
                       unsigned* __restrict__ Wp) {
    int row = blockIdx.x;                  // 0 .. NI*PROWS-1
    int l = row / PROWS;
    int b = row % PROWS;
    const unsigned short* src = Wt + ((size_t)l * TROWS + b) * H;
    unsigned* dst = Wp + ((size_t)l * PROWS + b) * H;
    int c = threadIdx.x;
    unsigned v = 0;
    if (b < NB) v = (unsigned)src[c] | ((unsigned)src[c + H] << 16);
    dst[c] = v;
}

// Aggregation: agg[i,c] = sum_j lerp(W, d_ij)[c] * h[j,c] (fp32 accum).
// Block = 1 atom, 4 waves split the (padded) neighbor list; lane owns 4
// channels. Double-buffered 4-neighbor chunks, 16 loads in flight per wave.
__global__ void __launch_bounds__(256) pair_k(
    const unsigned short* __restrict__ hbf, const unsigned* __restrict__ Wp,
    const float2* __restrict__ gmeta, const int* __restrict__ cnts,
    float* __restrict__ agg) {
    int tid = threadIdx.x;
    int wid = tid >> 6, lane = tid & 63;
    int c4 = lane * 4;
    int i = blockIdx.x;

    __shared__ __align__(8) float2 sMeta[CAP];
    __shared__ __align__(16) float sPart[4][H];

    int pc = cnts[i];                      // padded count (multiple of 32)
    for (int t = tid; t < pc; t += 256)
        sMeta[t] = gmeta[(size_t)i * CAP + t];
    __syncthreads();

    float4 acc = make_float4(0.f, 0.f, 0.f, 0.f);
    int chunks = pc >> 4;                  // per-wave chunks of 4 neighbors; even

    uint4 wA[4], wB[4];
    uint2 hA[4], hB[4];
    float tA[4], tB[4];

    auto issue = [&](int q, uint4 (&wr)[4], uint2 (&hr)[4], float (&tr)[4]) {
        #pragma unroll
        for (int s = 0; s < 4; ++s) {
            int n = wid + (q * 4 + s) * 4;        // wave-uniform -> LDS broadcast
            float2 mt = sMeta[n];
            int pk = __float_as_int(mt.x);
            tr[s] = mt.y;
            int j = pk & 1023;
            int bin = pk >> 10;
            wr[s] = *(const uint4*)(Wp + bin * H + c4);
            hr[s] = *(const uint2*)(hbf + j * H + c4);
        }
    };
    auto consume = [&](uint4 (&wr)[4], uint2 (&hr)[4], float (&tr)[4]) {
        #pragma unroll
        for (int s = 0; s < 4; ++s) {
            float t = tr[s];
            float w0, w1, hv;
            w0 = bf_lo(wr[s].x); w1 = bf_hi(wr[s].x); hv = bf_lo(hr[s].x);
            acc.x = fmaf(fmaf(t, w1 - w0, w0), hv, acc.x);
            w0 = bf_lo(wr[s].y); w1 = bf_hi(wr[s].y); hv = bf_hi(hr[s].x);
            acc.y = fmaf(fmaf(t, w1 - w0, w0), hv, acc.y);
            w0 = bf_lo(wr[s].z); w1 = bf_hi(wr[s].z); hv = bf_lo(hr[s].y);
            acc.z = fmaf(fmaf(t, w1 - w0, w0), hv, acc.z);
            w0 = bf_lo(wr[s].w); w1 = bf_hi(wr[s].w); hv = bf_hi(hr[s].y);
            acc.w = fmaf(fmaf(t, w1 - w0, w0), hv, acc.w);
        }
    };

    if (chunks > 0) {
        issue(0, wA, hA, tA);
        if (chunks > 1) issue(1, wB, hB, tB);
        for (int q = 0; q < chunks; q += 2) {
            consume(wA, hA, tA);
            if (q + 2 < chunks) issue(q + 2, wA, hA, tA);
            if (q + 1 < chunks) {
                consume(wB, hB, tB);
                if (q + 3 < chunks) issue(q + 3, wB, hB, tB);
            }
        }
    }
    *(float4*)&sPart[wid][c4] = acc;
    __syncthreads();
    agg[i * H + tid] = sPart[0][tid] + sPart[1][tid] + sPart[2][tid] + sPart[3][tid];
}

// Atom MLP: hout = hin + gelu(agg@aw1+ab1)@aw2+ab2 (also emits bf16 mirror).
// 512 threads = 8 waves; waves split K into eighths (32 rows each).
__global__ void __launch_bounds__(512) mlp_k(
    const float* __restrict__ agg, const float* __restrict__ hin,
    const float* __restrict__ aw1, const float* __restrict__ ab1,
    const float* __restrict__ aw2, const float* __restrict__ ab2,
    float* __restrict__ hout, unsigned short* __restrict__ hbf_out) {
    int tid = threadIdx.x;
    int wid = tid >> 6, lane = tid & 63;
    int c4 = lane * 4;
    int i0 = blockIdx.x * MATB;
    __shared__ __align__(16) float sAT[H][MATB];   // acts transposed [k][a]
    __shared__ __align__(16) float sGT[H][MATB];
    __shared__ __align__(16) float sPart[8][MATB][H];  // 32 KB

    if (tid < H) {
        #pragma unroll
        for (int r = 0; r < MATB; ++r)
            sAT[tid][r] = agg[(i0 + r) * H + tid];
    }
    __syncthreads();

    int k0 = wid * 32;
    float4 acc[MATB];
    #pragma unroll
    for (int a = 0; a < MATB; ++a) acc[a] = make_float4(0.f, 0.f, 0.f, 0.f);
    #pragma unroll 8
    for (int k = 0; k < 32; ++k) {
        float4 q = *(const float4*)(aw1 + (k0 + k) * H + c4);
        float4 act = *(const float4*)&sAT[k0 + k][0];
        FMA4(acc[0], act.x, q); FMA4(acc[1], act.y, q);
        FMA4(acc[2], act.z, q); FMA4(acc[3], act.w, q);
    }
    #pragma unroll
    for (int a = 0; a < MATB; ++a)
        *(float4*)&sPart[wid][a][c4] = acc[a];
    __syncthreads();
    if (tid < H) {
        float b1 = ab1[tid];
        float g[MATB];
        #pragma unroll
        for (int a = 0; a < MATB; ++a) {
            float v = b1;
            #pragma unroll
            for (int s = 0; s < 8; ++s) v += sPart[s][a][tid];
            g[a] = gelu_f(v);
        }
        *(float4*)&sGT[tid][0] = make_float4(g[0], g[1], g[2], g[3]);
    }
    __syncthreads();
    #pragma unroll
    for (int a = 0; a < MATB; ++a) acc[a] = make_float4(0.f, 0.f, 0.f, 0.f);
    #pragma unroll 8
    for (int k = 0; k < 32; ++k) {
        float4 q = *(const float4*)(aw2 + (k0 + k) * H + c4);
        float4 act = *(const float4*)&sGT[k0 + k][0];
        FMA4(acc[0], act.x, q); FMA4(acc[1], act.y, q);
        FMA4(acc[2], act.z, q); FMA4(acc[3], act.w, q);
    }
    #pragma unroll
    for (int a = 0; a < MATB; ++a)
        *(float4*)&sPart[wid][a][c4] = acc[a];
    __syncthreads();
    if (tid < H) {
        float b2 = ab2[tid];
        #pragma unroll
        for (int a = 0; a < MATB; ++a) {
            float v = b2;
            #pragma unroll
            for (int s = 0; s < 8; ++s) v += sPart[s][a][tid];
            float hv = hin[(i0 + a) * H + tid] + v;
            hout[(i0 + a) * H + tid] = hv;
            hbf_out[(i0 + a) * H + tid] = f2bf(hv);
        }
    }
}

// pooled -> gelu(pw1) -> pw2 -> layernorm. Block per molecule, waves split K.
__global__ void __launch_bounds__(256) head_k(
        const float* __restrict__ h,
        const float* __restrict__ pw1, const float* __restrict__ pb1,
        const float* __restrict__ pw2, const float* __restrict__ pb2,
        const float* __restrict__ ln_g, const float* __restrict__ ln_b,
        float* __restrict__ out) {
    int b = blockIdx.x, tid = threadIdx.x;
    int wid = tid >> 6, lane = tid & 63;
    int c4 = lane * 4;
    __shared__ float sP[H];
    __shared__ __align__(16) float sPw[4][H];
    __shared__ float sG[H];
    __shared__ __align__(16) float sP2[4][L];
    __shared__ float sX[L];
    __shared__ float sRed[256];

    float4 p = make_float4(0.f, 0.f, 0.f, 0.f);
    #pragma unroll 4
    for (int a = 0; a < 16; ++a) {
        float4 hv = *(const float4*)(h + (b * 64 + wid * 16 + a) * H + c4);
        p.x += hv.x; p.y += hv.y; p.z += hv.z; p.w += hv.w;
    }
    *(float4*)&sPw[wid][c4] = p;
    __syncthreads();
    sP[tid] = sPw[0][tid] + sPw[1][tid] + sPw[2][tid] + sPw[3][tid];
    __syncthreads();

    int k0 = wid * 64;
    float4 acc = make_float4(0.f, 0.f, 0.f, 0.f);
    #pragma unroll 8
    for (int k = 0; k < 64; ++k) {
        float4 q = *(const float4*)(pw1 + (k0 + k) * H + c4);
        float s = sP[k0 + k];
        FMA4(acc, s, q);
    }
    *(float4*)&sPw[wid][c4] = acc;
    __syncthreads();
    sG[tid] = gelu_f(pb1[tid] + sPw[0][tid] + sPw[1][tid] + sPw[2][tid] + sPw[3][tid]);
    __syncthreads();

    float4 a0 = make_float4(0.f, 0.f, 0.f, 0.f);
    float4 a1 = make_float4(0.f, 0.f, 0.f, 0.f);
    #pragma unroll 4
    for (int k = 0; k < 64; ++k) {
        float s = sG[k0 + k];
        float4 q0 = *(const float4*)(pw2 + (k0 + k) * L + lane * 8);
        float4 q1 = *(const float4*)(pw2 + (k0 + k) * L + lane * 8 + 4);
        FMA4(a0, s, q0);
        FMA4(a1, s, q1);
    }
    *(float4*)&sP2[wid][lane * 8] = a0;
    *(float4*)&sP2[wid][lane * 8 + 4] = a1;
    __syncthreads();
    for (int r = 0; r < 2; ++r) {
        int l = tid + r * 256;
        sX[l] = pb2[l] + sP2[0][l] + sP2[1][l] + sP2[2][l] + sP2[3][l];
    }
    __syncthreads();

    sRed[tid] = sX[tid] + sX[tid + 256];
    __syncthreads();
    for (int off = 128; off > 0; off >>= 1) {
        if (tid < off) sRed[tid] += sRed[tid + off];
        __syncthreads();
    }
    float mu = sRed[0] / (float)L;
    __syncthreads();
    float d0 = sX[tid] - mu, d1 = sX[tid + 256] - mu;
    sRed[tid] = d0 * d0 + d1 * d1;
    __syncthreads();
    for (int off = 128; off > 0; off >>= 1) {
        if (tid < off) sRed[tid] += sRed[tid + off];
        __syncthreads();
    }
    float var = sRed[0] / (float)L;
    float rstd = rsqrtf(var + 1e-5f);
    for (int r = 0; r < 2; ++r) {
        int l = tid + r * 256;
        out[b * L + l] = (sX[l] - mu) * rstd * ln_g[l] + ln_b[l];
    }
}

extern "C" void kernel_launch(void* const* d_in, const int* in_sizes, int n_in,
                              void* d_out, int out_size, void* d_ws, size_t ws_size,
                              hipStream_t stream) {
    const int*   z    = (const int*)d_in[0];
    const float* pos  = (const float*)d_in[1];
    // d_in[2] = batch: fixed arange//64 layout, handled implicitly in head_k
    const float* emb  = (const float*)d_in[3];
    const float* fw1  = (const float*)d_in[4];
    const float* fb1  = (const float*)d_in[5];
    const float* fw2  = (const float*)d_in[6];
    const float* fb2  = (const float*)d_in[7];
    const float* aw1  = (const float*)d_in[8];
    const float* ab1  = (const float*)d_in[9];
    const float* aw2  = (const float*)d_in[10];
    const float* ab2  = (const float*)d_in[11];
    const float* pw1  = (const float*)d_in[12];
    const float* pb1  = (const float*)d_in[13];
    const float* pw2  = (const float*)d_in[14];
    const float* pb2  = (const float*)d_in[15];
    const float* ln_g = (const float*)d_in[16];
    const float* ln_b = (const float*)d_in[17];
    float* out = (float*)d_out;

    float* hA  = (float*)d_ws;                        // [N][H] fp32
    float* hB  = hA + N * H;                          // [N][H] fp32
    float* agg = hB + N * H;                          // [N][H] fp32
    unsigned short* hbfA = (unsigned short*)(agg + N * H);   // [N][H] bf16
    unsigned short* hbfB = hbfA + N * H;                     // [N][H] bf16
    unsigned short* Wtb  = hbfB + N * H;              // [NI][TROWS][H] bf16
    unsigned* Wp = (unsigned*)(Wtb + (size_t)NI * TROWS * H); // [NI][PROWS][H]
    float2* meta = (float2*)(Wp + (size_t)NI * PROWS * H);    // [N][CAP]
    int* cnts = (int*)(meta + (size_t)N * CAP);               // [N]

    embed_k<<<N, H, 0, stream>>>(z, emb, hA, hbfA);
    nbrbuild_k<<<N, 256, 0, stream>>>(pos, meta, cnts);
    {
        int bpl = (TROWS + BPB - 1) / BPB;
        table_k<<<NI * bpl, 256, 0, stream>>>(fw1, fb1, fw2, fb2, Wtb);
        pack_k<<<NI * PROWS, 256, 0, stream>>>(Wtb, Wp);
    }
    float* hin = hA;  unsigned short* hbin = hbfA;
    float* hout = hB; unsigned short* hbout = hbfB;
    for (int it = 0; it < NI; ++it) {
        pair_k<<<N, 256, 0, stream>>>(hbin, Wp + (size_t)it * PROWS * H, meta, cnts, agg);
        mlp_k<<<N / MATB, 512, 0, stream>>>(agg, hin, aw1 + it * H * H, ab1 + it * H,
                                            aw2 + it * H * H, ab2 + it * H, hout, hbout);
        float* t1 = hin; hin = hout; hout = t1;
        unsigned short* t2 = hbin; hbin = hbout; hbout = t2;
    }
    head_k<<<B, 256, 0, stream>>>(hin, pw1, pb1, pw2, pb2, ln_g, ln_b, out);
}

// Round 8
// 270.053 us; speedup vs baseline: 1.9546x; 1.0418x over previous
//
#include <hip/hip_runtime.h>
#include <math.h>

#define N 1024
#define H 256
#define L 512
#define NG 50
#define NI 3
#define B 16
#define NB 2048            // distance-LUT bins over [0, CUT]
#define CUT 5.0f
#define BPB 16             // bins per block in table_k (4 per wave, 1 MFMA tile)
#define TROWS (NB + 1)     // 2049 rows per table (bf16 scalar table)
#define PROWS (NB + 1)     // packed-pair rows: 0..NB-1 pairs, NB = zero sentinel
#define MATB 4             // atoms per block in mlp_k
#define CAP 768            // max (padded) neighbors per atom
#define APAD 264           // padded LDS row (bf16) to break bank conflicts

typedef __attribute__((ext_vector_type(8))) short bf16x8;
typedef __attribute__((ext_vector_type(4))) float f32x4;

// NOTE: param must NOT be named 'w' — it would capture the '.w' member token.
#define FMA4(A_, S_, V_) do { \
    (A_).x = fmaf((S_), (V_).x, (A_).x); (A_).y = fmaf((S_), (V_).y, (A_).y); \
    (A_).z = fmaf((S_), (V_).z, (A_).z); (A_).w = fmaf((S_), (V_).w, (A_).w); } while (0)

__device__ __forceinline__ float gelu_f(float x) {
    return 0.5f * x * (1.0f + erff(x * 0.70710678118654752f));
}
__device__ __forceinline__ unsigned short f2bf(float f) {
    unsigned u = __float_as_uint(f);
    unsigned r = (u + 0x7fffu + ((u >> 16) & 1u)) >> 16;   // RNE
    return (unsigned short)r;
}
__device__ __forceinline__ float bf_lo(unsigned u) { return __uint_as_float(u << 16); }
__device__ __forceinline__ float bf_hi(unsigned u) { return __uint_as_float(u & 0xffff0000u); }

__global__ void embed_k(const int* __restrict__ z, const float* __restrict__ emb,
                        float* __restrict__ h, unsigned short* __restrict__ hbf) {
    int i = blockIdx.x, c = threadIdx.x;
    float v = emb[z[i] * H + c];
    h[i * H + c] = v;
    hbf[i * H + c] = f2bf(v);
}

// Build neighbor lists ONCE (identical for all NI iterations).
// meta[i][t] = {as_float(j | bin<<10), fr}; padded to x32 with zero-row sentinel.
__global__ void __launch_bounds__(256) nbrbuild_k(
        const float* __restrict__ pos, float2* __restrict__ meta,
        int* __restrict__ cnts) {
    int i = blockIdx.x;
    int tid = threadIdx.x;
    __shared__ int sCnt;
    __shared__ __align__(8) float2 sMeta[CAP];
    if (tid == 0) sCnt = 0;
    __syncthreads();
    float pix = pos[i * 3 + 0], piy = pos[i * 3 + 1], piz = pos[i * 3 + 2];
    const float invd = (float)NB / CUT;
    for (int r = 0; r < 4; ++r) {
        int j = tid + r * 256;
        float dx = pos[j * 3 + 0] - pix;
        float dy = pos[j * 3 + 1] - piy;
        float dz = pos[j * 3 + 2] - piz;
        float d = sqrtf(dx * dx + dy * dy + dz * dz);
        if (d < CUT && d > 1e-6f) {
            float u = d * invd;
            int bin = (int)u;
            if (bin > NB - 1) bin = NB - 1;
            float fr = u - (float)bin;
            int idx = atomicAdd(&sCnt, 1);
            sMeta[idx] = make_float2(__int_as_float(j | (bin << 10)), fr);
        }
    }
    __syncthreads();
    int cnt = sCnt;
    int pc = (cnt + 31) & ~31;
    for (int t = cnt + tid; t < pc; t += 256)
        sMeta[t] = make_float2(__int_as_float(i | (NB << 10)), 0.f);  // zero row
    __syncthreads();
    for (int t = tid; t < pc; t += 256)
        meta[(size_t)i * CAP + t] = sMeta[t];
    if (tid == 0) cnts[i] = pc;
}

// Transpose+convert fw2: Bt[l][ch][k] = bf16(fw2[l][k][ch]). Grid NI*H, 256 thr.
__global__ void bweights_k(const float* __restrict__ fw2,
                           unsigned short* __restrict__ Bt) {
    int blk = blockIdx.x;
    int l = blk / H, ch = blk % H;
    int k = threadIdx.x;
    float v = fw2[((size_t)l * H + k) * H + ch];
    Bt[((size_t)l * H + ch) * H + k] = f2bf(v);
}

// Build all NI tables (bf16 out). grid = NI*129, 16 bins/block.
// Layer 1: fp32 VALU (K=50). Layer 2: bf16 MFMA 16x16x32, B from Bt (fw2^T).
__global__ void __launch_bounds__(256) table_k(
        const float* __restrict__ fw1, const float* __restrict__ fb1,
        const unsigned short* __restrict__ Bt, const float* __restrict__ fb2,
        unsigned short* __restrict__ Wtb) {
    const int bpl = (TROWS + BPB - 1) / BPB;      // 129 blocks per layer
    int layer = blockIdx.x / bpl;
    int blk = blockIdx.x % bpl;
    int b0 = blk * BPB;
    int tid = threadIdx.x;
    int wid = tid >> 6, lane = tid & 63;
    int c4 = lane * 4;
    int ub = wid * 4;                             // wave's first bin slot (layer 1)
    const float* lfw1 = fw1 + layer * NG * H;
    unsigned short* lWt = Wtb + (size_t)layer * TROWS * H;

    __shared__ __align__(16) float sRbf[BPB][56];
    __shared__ __align__(16) unsigned short sAb[BPB][APAD];  // gelu acts, bf16
    const float delta = CUT / (float)NB;
    for (int idx = tid; idx < BPB * NG; idx += 256) {
        int u = idx & 15;
        int k = idx >> 4;
        float d = (float)(b0 + u) * delta;
        float t = d - (float)k * (CUT / 49.0f);   // centers = linspace(0,5,50)
        sRbf[u][k] = expf(t * t * -200.0f);       // -1/(2*0.05^2)
    }
    __syncthreads();

    // layer 1: rbf @ fw1 (K = 50 = 12 quads + 2), wave owns 4 bins, lane 4 ch
    float4 acc1[4];
    #pragma unroll
    for (int u = 0; u < 4; ++u) acc1[u] = make_float4(0.f, 0.f, 0.f, 0.f);
    for (int kq = 0; kq < 12; ++kq) {
        int k = kq * 4;
        float4 r0 = *(const float4*)&sRbf[ub + 0][k];
        float4 r1 = *(const float4*)&sRbf[ub + 1][k];
        float4 r2 = *(const float4*)&sRbf[ub + 2][k];
        float4 r3 = *(const float4*)&sRbf[ub + 3][k];
        float4 q0 = *(const float4*)(lfw1 + (k + 0) * H + c4);
        float4 q1 = *(const float4*)(lfw1 + (k + 1) * H + c4);
        float4 q2 = *(const float4*)(lfw1 + (k + 2) * H + c4);
        float4 q3 = *(const float4*)(lfw1 + (k + 3) * H + c4);
        FMA4(acc1[0], r0.x, q0); FMA4(acc1[0], r0.y, q1);
        FMA4(acc1[0], r0.z, q2); FMA4(acc1[0], r0.w, q3);
        FMA4(acc1[1], r1.x, q0); FMA4(acc1[1], r1.y, q1);
        FMA4(acc1[1], r1.z, q2); FMA4(acc1[1], r1.w, q3);
        FMA4(acc1[2], r2.x, q0); FMA4(acc1[2], r2.y, q1);
        FMA4(acc1[2], r2.z, q2); FMA4(acc1[2], r2.w, q3);
        FMA4(acc1[3], r3.x, q0); FMA4(acc1[3], r3.y, q1);
        FMA4(acc1[3], r3.z, q2); FMA4(acc1[3], r3.w, q3);
    }
    for (int k = 48; k < NG; ++k) {
        float4 q = *(const float4*)(lfw1 + k * H + c4);
        #pragma unroll
        for (int u = 0; u < 4; ++u) FMA4(acc1[u], sRbf[ub + u][k], q);
    }
    float4 b1 = *(const float4*)(fb1 + layer * H + c4);
    #pragma unroll
    for (int u = 0; u < 4; ++u) {
        ushort4 g;
        g.x = f2bf(gelu_f(acc1[u].x + b1.x));
        g.y = f2bf(gelu_f(acc1[u].y + b1.y));
        g.z = f2bf(gelu_f(acc1[u].z + b1.z));
        g.w = f2bf(gelu_f(acc1[u].w + b1.w));
        *(ushort4*)&sAb[ub + u][c4] = g;
    }
    __syncthreads();

    // layer 2: MFMA. One 16-bin tile; wave wid covers ch-tiles 4*wid..4*wid+3.
    // A[m][k]: m = lane&15 (bin), k = quad*8+j  (m120-verified A layout)
    // B[k][n]: n = lane&15 (ch) -> row n of Bt, k = quad*8+j
    // D[m][n]: col = lane&15, row = quad*4+reg  (m89-verified C/D layout)
    int m = lane & 15;
    int quad = lane >> 4;
    bf16x8 afr[8];
    #pragma unroll
    for (int c = 0; c < 8; ++c)
        afr[c] = *(const bf16x8*)&sAb[m][c * 32 + quad * 8];
    #pragma unroll
    for (int ct = 0; ct < 4; ++ct) {
        int chn = (wid * 4 + ct) * 16 + m;
        const bf16x8* Bv = (const bf16x8*)(Bt + ((size_t)layer * H + chn) * H);
        f32x4 acc = {0.f, 0.f, 0.f, 0.f};
        #pragma unroll
        for (int c = 0; c < 8; ++c)
            acc = __builtin_amdgcn_mfma_f32_16x16x32_bf16(afr[c], Bv[c * 4 + quad],
                                                          acc, 0, 0, 0);
        float bias = fb2[layer * H + chn];
        #pragma unroll
        for (int r = 0; r < 4; ++r) {
            int bin = b0 + quad * 4 + r;
            if (bin < TROWS)
                lWt[(size_t)bin * H + chn] = f2bf(acc[r] + bias);
        }
    }
}

// Pack lerp row pairs: Wp[l][b][c] = Wt[l][b][c] | (Wt[l][b+1][c] << 16).
// Row b == NB is the zero sentinel (used by padded neighbor slots).
__global__ void pack_k(const unsigned short* __restrict__ Wt,
                       unsigned* __restrict__ Wp) {
    int row = blockIdx.x;                  // 0 .. NI*PROWS-1
    int l = row / PROWS;
    int b = row % PROWS;
    const unsigned short* src = Wt + ((size_t)l * TROWS + b) * H;
    unsigned* dst = Wp + ((size_t)l * PROWS + b) * H;
    int c = threadIdx.x;
    unsigned v = 0;
    if (b < NB) v = (unsigned)src[c] | ((unsigned)src[c + H] << 16);
    dst[c] = v;
}

// Aggregation: agg[i,c] = sum_j lerp(W, d_ij)[c] * h[j,c] (fp32 accum).
// Block = 1 atom, 4 waves split the (padded) neighbor list; lane owns 4
// channels. Double-buffered 4-neighbor chunks, 16 loads in flight per wave.
__global__ void __launch_bounds__(256) pair_k(
    const unsigned short* __restrict__ hbf, const unsigned* __restrict__ Wp,
    const float2* __restrict__ gmeta, const int* __restrict__ cnts,
    float* __restrict__ agg) {
    int tid = threadIdx.x;
    int wid = tid >> 6, lane = tid & 63;
    int c4 = lane * 4;
    int i = blockIdx.x;

    __shared__ __align__(8) float2 sMeta[CAP];
    __shared__ __align__(16) float sPart[4][H];

    int pc = cnts[i];                      // padded count (multiple of 32)
    for (int t = tid; t < pc; t += 256)
        sMeta[t] = gmeta[(size_t)i * CAP + t];
    __syncthreads();

    float4 acc = make_float4(0.f, 0.f, 0.f, 0.f);
    int chunks = pc >> 4;                  // per-wave chunks of 4 neighbors; even

    uint4 wA[4], wB[4];
    uint2 hA[4], hB[4];
    float tA[4], tB[4];

    auto issue = [&](int q, uint4 (&wr)[4], uint2 (&hr)[4], float (&tr)[4]) {
        #pragma unroll
        for (int s = 0; s < 4; ++s) {
            int n = wid + (q * 4 + s) * 4;        // wave-uniform -> LDS broadcast
            float2 mt = sMeta[n];
            int pk = __float_as_int(mt.x);
            tr[s] = mt.y;
            int j = pk & 1023;
            int bin = pk >> 10;
            wr[s] = *(const uint4*)(Wp + bin * H + c4);
            hr[s] = *(const uint2*)(hbf + j * H + c4);
        }
    };
    auto consume = [&](uint4 (&wr)[4], uint2 (&hr)[4], float (&tr)[4]) {
        #pragma unroll
        for (int s = 0; s < 4; ++s) {
            float t = tr[s];
            float w0, w1, hv;
            w0 = bf_lo(wr[s].x); w1 = bf_hi(wr[s].x); hv = bf_lo(hr[s].x);
            acc.x = fmaf(fmaf(t, w1 - w0, w0), hv, acc.x);
            w0 = bf_lo(wr[s].y); w1 = bf_hi(wr[s].y); hv = bf_hi(hr[s].x);
            acc.y = fmaf(fmaf(t, w1 - w0, w0), hv, acc.y);
            w0 = bf_lo(wr[s].z); w1 = bf_hi(wr[s].z); hv = bf_lo(hr[s].y);
            acc.z = fmaf(fmaf(t, w1 - w0, w0), hv, acc.z);
            w0 = bf_lo(wr[s].w); w1 = bf_hi(wr[s].w); hv = bf_hi(hr[s].y);
            acc.w = fmaf(fmaf(t, w1 - w0, w0), hv, acc.w);
        }
    };

    if (chunks > 0) {
        issue(0, wA, hA, tA);
        if (chunks > 1) issue(1, wB, hB, tB);
        for (int q = 0; q < chunks; q += 2) {
            consume(wA, hA, tA);
            if (q + 2 < chunks) issue(q + 2, wA, hA, tA);
            if (q + 1 < chunks) {
                consume(wB, hB, tB);
                if (q + 3 < chunks) issue(q + 3, wB, hB, tB);
            }
        }
    }
    *(float4*)&sPart[wid][c4] = acc;
    __syncthreads();
    agg[i * H + tid] = sPart[0][tid] + sPart[1][tid] + sPart[2][tid] + sPart[3][tid];
}

// Atom MLP: hout = hin + gelu(agg@aw1+ab1)@aw2+ab2 (also emits bf16 mirror).
// 512 threads = 8 waves; waves split K into eighths (32 rows each).
__global__ void __launch_bounds__(512) mlp_k(
    const float* __restrict__ agg, const float* __restrict__ hin,
    const float* __restrict__ aw1, const float* __restrict__ ab1,
    const float* __restrict__ aw2, const float* __restrict__ ab2,
    float* __restrict__ hout, unsigned short* __restrict__ hbf_out) {
    int tid = threadIdx.x;
    int wid = tid >> 6, lane = tid & 63;
    int c4 = lane * 4;
    int i0 = blockIdx.x * MATB;
    __shared__ __align__(16) float sAT[H][MATB];   // acts transposed [k][a]
    __shared__ __align__(16) float sGT[H][MATB];
    __shared__ __align__(16) float sPart[8][MATB][H];  // 32 KB

    if (tid < H) {
        #pragma unroll
        for (int r = 0; r < MATB; ++r)
            sAT[tid][r] = agg[(i0 + r) * H + tid];
    }
    __syncthreads();

    int k0 = wid * 32;
    float4 acc[MATB];
    #pragma unroll
    for (int a = 0; a < MATB; ++a) acc[a] = make_float4(0.f, 0.f, 0.f, 0.f);
    #pragma unroll 8
    for (int k = 0; k < 32; ++k) {
        float4 q = *(const float4*)(aw1 + (k0 + k) * H + c4);
        float4 act = *(const float4*)&sAT[k0 + k][0];
        FMA4(acc[0], act.x, q); FMA4(acc[1], act.y, q);
        FMA4(acc[2], act.z, q); FMA4(acc[3], act.w, q);
    }
    #pragma unroll
    for (int a = 0; a < MATB; ++a)
        *(float4*)&sPart[wid][a][c4] = acc[a];
    __syncthreads();
    if (tid < H) {
        float b1 = ab1[tid];
        float g[MATB];
        #pragma unroll
        for (int a = 0; a < MATB; ++a) {
            float v = b1;
            #pragma unroll
            for (int s = 0; s < 8; ++s) v += sPart[s][a][tid];
            g[a] = gelu_f(v);
        }
        *(float4*)&sGT[tid][0] = make_float4(g[0], g[1], g[2], g[3]);
    }
    __syncthreads();
    #pragma unroll
    for (int a = 0; a < MATB; ++a) acc[a] = make_float4(0.f, 0.f, 0.f, 0.f);
    #pragma unroll 8
    for (int k = 0; k < 32; ++k) {
        float4 q = *(const float4*)(aw2 + (k0 + k) * H + c4);
        float4 act = *(const float4*)&sGT[k0 + k][0];
        FMA4(acc[0], act.x, q); FMA4(acc[1], act.y, q);
        FMA4(acc[2], act.z, q); FMA4(acc[3], act.w, q);
    }
    #pragma unroll
    for (int a = 0; a < MATB; ++a)
        *(float4*)&sPart[wid][a][c4] = acc[a];
    __syncthreads();
    if (tid < H) {
        float b2 = ab2[tid];
        #pragma unroll
        for (int a = 0; a < MATB; ++a) {
            float v = b2;
            #pragma unroll
            for (int s = 0; s < 8; ++s) v += sPart[s][a][tid];
            float hv = hin[(i0 + a) * H + tid] + v;
            hout[(i0 + a) * H + tid] = hv;
            hbf_out[(i0 + a) * H + tid] = f2bf(hv);
        }
    }
}

// pooled -> gelu(pw1) -> pw2 -> layernorm. Block per molecule, waves split K.
__global__ void __launch_bounds__(256) head_k(
        const float* __restrict__ h,
        const float* __restrict__ pw1, const float* __restrict__ pb1,
        const float* __restrict__ pw2, const float* __restrict__ pb2,
        const float* __restrict__ ln_g, const float* __restrict__ ln_b,
        float* __restrict__ out) {
    int b = blockIdx.x, tid = threadIdx.x;
    int wid = tid >> 6, lane = tid & 63;
    int c4 = lane * 4;
    __shared__ float sP[H];
    __shared__ __align__(16) float sPw[4][H];
    __shared__ float sG[H];
    __shared__ __align__(16) float sP2[4][L];
    __shared__ float sX[L];
    __shared__ float sRed[256];

    float4 p = make_float4(0.f, 0.f, 0.f, 0.f);
    #pragma unroll 4
    for (int a = 0; a < 16; ++a) {
        float4 hv = *(const float4*)(h + (b * 64 + wid * 16 + a) * H + c4);
        p.x += hv.x; p.y += hv.y; p.z += hv.z; p.w += hv.w;
    }
    *(float4*)&sPw[wid][c4] = p;
    __syncthreads();
    sP[tid] = sPw[0][tid] + sPw[1][tid] + sPw[2][tid] + sPw[3][tid];
    __syncthreads();

    int k0 = wid * 64;
    float4 acc = make_float4(0.f, 0.f, 0.f, 0.f);
    #pragma unroll 8
    for (int k = 0; k < 64; ++k) {
        float4 q = *(const float4*)(pw1 + (k0 + k) * H + c4);
        float s = sP[k0 + k];
        FMA4(acc, s, q);
    }
    *(float4*)&sPw[wid][c4] = acc;
    __syncthreads();
    sG[tid] = gelu_f(pb1[tid] + sPw[0][tid] + sPw[1][tid] + sPw[2][tid] + sPw[3][tid]);
    __syncthreads();

    float4 a0 = make_float4(0.f, 0.f, 0.f, 0.f);
    float4 a1 = make_float4(0.f, 0.f, 0.f, 0.f);
    #pragma unroll 4
    for (int k = 0; k < 64; ++k) {
        float s = sG[k0 + k];
        float4 q0 = *(const float4*)(pw2 + (k0 + k) * L + lane * 8);
        float4 q1 = *(const float4*)(pw2 + (k0 + k) * L + lane * 8 + 4);
        FMA4(a0, s, q0);
        FMA4(a1, s, q1);
    }
    *(float4*)&sP2[wid][lane * 8] = a0;
    *(float4*)&sP2[wid][lane * 8 + 4] = a1;
    __syncthreads();
    for (int r = 0; r < 2; ++r) {
        int l = tid + r * 256;
        sX[l] = pb2[l] + sP2[0][l] + sP2[1][l] + sP2[2][l] + sP2[3][l];
    }
    __syncthreads();

    sRed[tid] = sX[tid] + sX[tid + 256];
    __syncthreads();
    for (int off = 128; off > 0; off >>= 1) {
        if (tid < off) sRed[tid] += sRed[tid + off];
        __syncthreads();
    }
    float mu = sRed[0] / (float)L;
    __syncthreads();
    float d0 = sX[tid] - mu, d1 = sX[tid + 256] - mu;
    sRed[tid] = d0 * d0 + d1 * d1;
    __syncthreads();
    for (int off = 128; off > 0; off >>= 1) {
        if (tid < off) sRed[tid] += sRed[tid + off];
        __syncthreads();
    }
    float var = sRed[0] / (float)L;
    float rstd = rsqrtf(var + 1e-5f);
    for (int r = 0; r < 2; ++r) {
        int l = tid + r * 256;
        out[b * L + l] = (sX[l] - mu) * rstd * ln_g[l] + ln_b[l];
    }
}

extern "C" void kernel_launch(void* const* d_in, const int* in_sizes, int n_in,
                              void* d_out, int out_size, void* d_ws, size_t ws_size,
                              hipStream_t stream) {
    const int*   z    = (const int*)d_in[0];
    const float* pos  = (const float*)d_in[1];
    // d_in[2] = batch: fixed arange//64 layout, handled implicitly in head_k
    const float* emb  = (const float*)d_in[3];
    const float* fw1  = (const float*)d_in[4];
    const float* fb1  = (const float*)d_in[5];
    const float* fw2  = (const float*)d_in[6];
    const float* fb2  = (const float*)d_in[7];
    const float* aw1  = (const float*)d_in[8];
    const float* ab1  = (const float*)d_in[9];
    const float* aw2  = (const float*)d_in[10];
    const float* ab2  = (const float*)d_in[11];
    const float* pw1  = (const float*)d_in[12];
    const float* pb1  = (const float*)d_in[13];
    const float* pw2  = (const float*)d_in[14];
    const float* pb2  = (const float*)d_in[15];
    const float* ln_g = (const float*)d_in[16];
    const float* ln_b = (const float*)d_in[17];
    float* out = (float*)d_out;

    float* hA  = (float*)d_ws;                        // [N][H] fp32
    float* hB  = hA + N * H;                          // [N][H] fp32
    float* agg = hB + N * H;                          // [N][H] fp32
    unsigned short* hbfA = (unsigned short*)(agg + N * H);   // [N][H] bf16
    unsigned short* hbfB = hbfA + N * H;                     // [N][H] bf16
    unsigned short* Wtb  = hbfB + N * H;              // [NI][TROWS][H] bf16
    unsigned* Wp = (unsigned*)(Wtb + (size_t)NI * TROWS * H); // [NI][PROWS][H]
    float2* meta = (float2*)(Wp + (size_t)NI * PROWS * H);    // [N][CAP]
    int* cnts = (int*)(meta + (size_t)N * CAP);               // [N]
    unsigned short* Bt = (unsigned short*)(cnts + N);         // [NI][H][H] bf16

    embed_k<<<N, H, 0, stream>>>(z, emb, hA, hbfA);
    nbrbuild_k<<<N, 256, 0, stream>>>(pos, meta, cnts);
    bweights_k<<<NI * H, 256, 0, stream>>>(fw2, Bt);
    {
        int bpl = (TROWS + BPB - 1) / BPB;
        table_k<<<NI * bpl, 256, 0, stream>>>(fw1, fb1, Bt, fb2, Wtb);
        pack_k<<<NI * PROWS, 256, 0, stream>>>(Wtb, Wp);
    }
    float* hin = hA;  unsigned short* hbin = hbfA;
    float* hout = hB; unsigned short* hbout = hbfB;
    for (int it = 0; it < NI; ++it) {
        pair_k<<<N, 256, 0, stream>>>(hbin, Wp + (size_t)it * PROWS * H, meta, cnts, agg);
        mlp_k<<<N / MATB, 512, 0, stream>>>(agg, hin, aw1 + it * H * H, ab1 + it * H,
                                            aw2 + it * H * H, ab2 + it * H, hout, hbout);
        float* t1 = hin; hin = hout; hout = t1;
        unsigned short* t2 = hbin; hbin = hbout; hbout = t2;
    }
    head_k<<<B, 256, 0, stream>>>(hin, pw1, pb1, pw2, pb2, ln_g, ln_b, out);
}

// Round 9
// 268.925 us; speedup vs baseline: 1.9628x; 1.0042x over previous
//
#include <hip/hip_runtime.h>
#include <hip/hip_fp16.h>
#include <math.h>

#define N 1024
#define H 256
#define L 512
#define NG 50
#define NI 3
#define B 16
#define NB 2048            // distance-LUT bins over [0, CUT]
#define CUT 5.0f
#define BPB 16             // bins per block in table_k (4 per wave, 1 MFMA tile)
#define TROWS (NB + 1)     // 2049 rows per table (fp16 scalar table)
#define PROWS (NB + 1)     // packed rows: 0..NB-1 = (w0,dw), NB = zero sentinel
#define MATB 4             // atoms per block in mlp_k
#define CAP 768            // max (padded) neighbors per atom
#define APAD 264           // padded LDS row (bf16) to break bank conflicts

typedef __attribute__((ext_vector_type(8))) short bf16x8;
typedef __attribute__((ext_vector_type(4))) float f32x4;

// NOTE: param must NOT be named 'w' — it would capture the '.w' member token.
#define FMA4(A_, S_, V_) do { \
    (A_).x = fmaf((S_), (V_).x, (A_).x); (A_).y = fmaf((S_), (V_).y, (A_).y); \
    (A_).z = fmaf((S_), (V_).z, (A_).z); (A_).w = fmaf((S_), (V_).w, (A_).w); } while (0)

__device__ __forceinline__ float gelu_f(float x) {
    return 0.5f * x * (1.0f + erff(x * 0.70710678118654752f));
}
__device__ __forceinline__ unsigned short f2bf(float f) {
    unsigned u = __float_as_uint(f);
    unsigned r = (u + 0x7fffu + ((u >> 16) & 1u)) >> 16;   // RNE
    return (unsigned short)r;
}

__global__ void embed_k(const int* __restrict__ z, const float* __restrict__ emb,
                        float* __restrict__ h, __half* __restrict__ hhf) {
    int i = blockIdx.x, c = threadIdx.x;
    float v = emb[z[i] * H + c];
    h[i * H + c] = v;
    hhf[i * H + c] = __float2half(v);
}

// Build neighbor lists ONCE (identical for all NI iterations).
// meta[i][t] = {as_float(j | bin<<10), fr}; padded to x32 with zero-row sentinel.
__global__ void __launch_bounds__(256) nbrbuild_k(
        const float* __restrict__ pos, float2* __restrict__ meta,
        int* __restrict__ cnts) {
    int i = blockIdx.x;
    int tid = threadIdx.x;
    __shared__ int sCnt;
    __shared__ __align__(8) float2 sMeta[CAP];
    if (tid == 0) sCnt = 0;
    __syncthreads();
    float pix = pos[i * 3 + 0], piy = pos[i * 3 + 1], piz = pos[i * 3 + 2];
    const float invd = (float)NB / CUT;
    for (int r = 0; r < 4; ++r) {
        int j = tid + r * 256;
        float dx = pos[j * 3 + 0] - pix;
        float dy = pos[j * 3 + 1] - piy;
        float dz = pos[j * 3 + 2] - piz;
        float d = sqrtf(dx * dx + dy * dy + dz * dz);
        if (d < CUT && d > 1e-6f) {
            float u = d * invd;
            int bin = (int)u;
            if (bin > NB - 1) bin = NB - 1;
            float fr = u - (float)bin;
            int idx = atomicAdd(&sCnt, 1);
            sMeta[idx] = make_float2(__int_as_float(j | (bin << 10)), fr);
        }
    }
    __syncthreads();
    int cnt = sCnt;
    int pc = (cnt + 31) & ~31;
    for (int t = cnt + tid; t < pc; t += 256)
        sMeta[t] = make_float2(__int_as_float(i | (NB << 10)), 0.f);  // zero row
    __syncthreads();
    for (int t = tid; t < pc; t += 256)
        meta[(size_t)i * CAP + t] = sMeta[t];
    if (tid == 0) cnts[i] = pc;
}

// Transpose+convert fw2: Bt[l][ch][k] = bf16(fw2[l][k][ch]). Grid NI*H, 256 thr.
__global__ void bweights_k(const float* __restrict__ fw2,
                           unsigned short* __restrict__ Bt) {
    int blk = blockIdx.x;
    int l = blk / H, ch = blk % H;
    int k = threadIdx.x;
    float v = fw2[((size_t)l * H + k) * H + ch];
    Bt[((size_t)l * H + ch) * H + k] = f2bf(v);
}

// Build all NI tables (fp16 out). grid = NI*129, 16 bins/block.
// Layer 1: fp32 VALU (K=50). Layer 2: bf16 MFMA 16x16x32, B from Bt (fw2^T).
__global__ void __launch_bounds__(256) table_k(
        const float* __restrict__ fw1, const float* __restrict__ fb1,
        const unsigned short* __restrict__ Bt, const float* __restrict__ fb2,
        __half* __restrict__ Wtb) {
    const int bpl = (TROWS + BPB - 1) / BPB;      // 129 blocks per layer
    int layer = blockIdx.x / bpl;
    int blk = blockIdx.x % bpl;
    int b0 = blk * BPB;
    int tid = threadIdx.x;
    int wid = tid >> 6, lane = tid & 63;
    int c4 = lane * 4;
    int ub = wid * 4;                             // wave's first bin slot (layer 1)
    const float* lfw1 = fw1 + layer * NG * H;
    __half* lWt = Wtb + (size_t)layer * TROWS * H;

    __shared__ __align__(16) float sRbf[BPB][56];
    __shared__ __align__(16) unsigned short sAb[BPB][APAD];  // gelu acts, bf16
    const float delta = CUT / (float)NB;
    for (int idx = tid; idx < BPB * NG; idx += 256) {
        int u = idx & 15;
        int k = idx >> 4;
        float d = (float)(b0 + u) * delta;
        float t = d - (float)k * (CUT / 49.0f);   // centers = linspace(0,5,50)
        sRbf[u][k] = expf(t * t * -200.0f);       // -1/(2*0.05^2)
    }
    __syncthreads();

    // layer 1: rbf @ fw1 (K = 50 = 12 quads + 2), wave owns 4 bins, lane 4 ch
    float4 acc1[4];
    #pragma unroll
    for (int u = 0; u < 4; ++u) acc1[u] = make_float4(0.f, 0.f, 0.f, 0.f);
    for (int kq = 0; kq < 12; ++kq) {
        int k = kq * 4;
        float4 r0 = *(const float4*)&sRbf[ub + 0][k];
        float4 r1 = *(const float4*)&sRbf[ub + 1][k];
        float4 r2 = *(const float4*)&sRbf[ub + 2][k];
        float4 r3 = *(const float4*)&sRbf[ub + 3][k];
        float4 q0 = *(const float4*)(lfw1 + (k + 0) * H + c4);
        float4 q1 = *(const float4*)(lfw1 + (k + 1) * H + c4);
        float4 q2 = *(const float4*)(lfw1 + (k + 2) * H + c4);
        float4 q3 = *(const float4*)(lfw1 + (k + 3) * H + c4);
        FMA4(acc1[0], r0.x, q0); FMA4(acc1[0], r0.y, q1);
        FMA4(acc1[0], r0.z, q2); FMA4(acc1[0], r0.w, q3);
        FMA4(acc1[1], r1.x, q0); FMA4(acc1[1], r1.y, q1);
        FMA4(acc1[1], r1.z, q2); FMA4(acc1[1], r1.w, q3);
        FMA4(acc1[2], r2.x, q0); FMA4(acc1[2], r2.y, q1);
        FMA4(acc1[2], r2.z, q2); FMA4(acc1[2], r2.w, q3);
        FMA4(acc1[3], r3.x, q0); FMA4(acc1[3], r3.y, q1);
        FMA4(acc1[3], r3.z, q2); FMA4(acc1[3], r3.w, q3);
    }
    for (int k = 48; k < NG; ++k) {
        float4 q = *(const float4*)(lfw1 + k * H + c4);
        #pragma unroll
        for (int u = 0; u < 4; ++u) FMA4(acc1[u], sRbf[ub + u][k], q);
    }
    float4 b1 = *(const float4*)(fb1 + layer * H + c4);
    #pragma unroll
    for (int u = 0; u < 4; ++u) {
        ushort4 g;
        g.x = f2bf(gelu_f(acc1[u].x + b1.x));
        g.y = f2bf(gelu_f(acc1[u].y + b1.y));
        g.z = f2bf(gelu_f(acc1[u].z + b1.z));
        g.w = f2bf(gelu_f(acc1[u].w + b1.w));
        *(ushort4*)&sAb[ub + u][c4] = g;
    }
    __syncthreads();

    // layer 2: MFMA. One 16-bin tile; wave wid covers ch-tiles 4*wid..4*wid+3.
    int m = lane & 15;
    int quad = lane >> 4;
    bf16x8 afr[8];
    #pragma unroll
    for (int c = 0; c < 8; ++c)
        afr[c] = *(const bf16x8*)&sAb[m][c * 32 + quad * 8];
    #pragma unroll
    for (int ct = 0; ct < 4; ++ct) {
        int chn = (wid * 4 + ct) * 16 + m;
        const bf16x8* Bv = (const bf16x8*)(Bt + ((size_t)layer * H + chn) * H);
        f32x4 acc = {0.f, 0.f, 0.f, 0.f};
        #pragma unroll
        for (int c = 0; c < 8; ++c)
            acc = __builtin_amdgcn_mfma_f32_16x16x32_bf16(afr[c], Bv[c * 4 + quad],
                                                          acc, 0, 0, 0);
        float bias = fb2[layer * H + chn];
        #pragma unroll
        for (int r = 0; r < 4; ++r) {
            int bin = b0 + quad * 4 + r;
            if (bin < TROWS)
                lWt[(size_t)bin * H + chn] = __float2half(acc[r] + bias);
        }
    }
}

// Pack lerp pairs: Wp[l][b][c] = (fp16 w0, fp16 (w1-w0)).
// Row b == NB is the zero sentinel (used by padded neighbor slots).
__global__ void pack_k(const __half* __restrict__ Wt,
                       __half2* __restrict__ Wp) {
    int row = blockIdx.x;                  // 0 .. NI*PROWS-1
    int l = row / PROWS;
    int b = row % PROWS;
    const __half* src = Wt + ((size_t)l * TROWS + b) * H;
    __half2* dst = Wp + ((size_t)l * PROWS + b) * H;
    int c = threadIdx.x;
    __half2 v;
    v.x = __float2half(0.f);
    v.y = __float2half(0.f);
    if (b < NB) {
        float w0 = __half2float(src[c]);
        float w1 = __half2float(src[c + H]);
        v.x = __float2half(w0);
        v.y = __float2half(w1 - w0);
    }
    dst[c] = v;
}

// Aggregation: agg[i,c] = sum_j lerp(W, d_ij)[c] * h[j,c] (fp32 accum).
// Block = 1 atom, 4 waves split the (padded) neighbor list; lane owns 4
// channels. fp16 consume: v_fma_f16 lerp + v_fma_mix_f32 accumulate.
__global__ void __launch_bounds__(256) pair_k(
    const __half* __restrict__ hhf, const unsigned* __restrict__ Wp,
    const float2* __restrict__ gmeta, const int* __restrict__ cnts,
    float* __restrict__ agg) {
    int tid = threadIdx.x;
    int wid = tid >> 6, lane = tid & 63;
    int c4 = lane * 4;
    int i = blockIdx.x;

    __shared__ __align__(8) float2 sMeta[CAP];
    __shared__ __align__(16) float sPart[4][H];

    int pc = cnts[i];                      // padded count (multiple of 32)
    for (int t = tid; t < pc; t += 256)
        sMeta[t] = gmeta[(size_t)i * CAP + t];
    __syncthreads();

    float4 acc = make_float4(0.f, 0.f, 0.f, 0.f);
    int chunks = pc >> 4;                  // per-wave chunks of 4 neighbors; even

    uint4 wA[4], wB[4];
    uint2 hA[4], hB[4];
    float tA[4], tB[4];

    auto issue = [&](int q, uint4 (&wr)[4], uint2 (&hr)[4], float (&tr)[4]) {
        #pragma unroll
        for (int s = 0; s < 4; ++s) {
            int n = wid + (q * 4 + s) * 4;        // wave-uniform -> LDS broadcast
            float2 mt = sMeta[n];
            int pk = __float_as_int(mt.x);
            tr[s] = mt.y;
            int j = pk & 1023;
            int bin = pk >> 10;
            wr[s] = *(const uint4*)(Wp + (size_t)bin * H + c4);   // 4x (w0,dw)
            hr[s] = *(const uint2*)(hhf + (size_t)j * H + c4);    // 4x fp16 h
        }
    };
    auto consume = [&](uint4 (&wr)[4], uint2 (&hr)[4], float (&tr)[4]) {
        #pragma unroll
        for (int s = 0; s < 4; ++s) {
            __half th = __float2half(tr[s]);
            __half2 p0 = *(__half2*)&wr[s].x;
            __half2 p1 = *(__half2*)&wr[s].y;
            __half2 p2 = *(__half2*)&wr[s].z;
            __half2 p3 = *(__half2*)&wr[s].w;
            __half2 h01 = *(__half2*)&hr[s].x;
            __half2 h23 = *(__half2*)&hr[s].y;
            __half e0 = __hfma(th, p0.y, p0.x);   // v_fma_f16 (op_sel hi)
            __half e1 = __hfma(th, p1.y, p1.x);
            __half e2 = __hfma(th, p2.y, p2.x);
            __half e3 = __hfma(th, p3.y, p3.x);
            acc.x += __half2float(e0) * __half2float(h01.x);  // v_fma_mix_f32
            acc.y += __half2float(e1) * __half2float(h01.y);
            acc.z += __half2float(e2) * __half2float(h23.x);
            acc.w += __half2float(e3) * __half2float(h23.y);
        }
    };

    if (chunks > 0) {
        issue(0, wA, hA, tA);
        if (chunks > 1) issue(1, wB, hB, tB);
        for (int q = 0; q < chunks; q += 2) {
            consume(wA, hA, tA);
            if (q + 2 < chunks) issue(q + 2, wA, hA, tA);
            if (q + 1 < chunks) {
                consume(wB, hB, tB);
                if (q + 3 < chunks) issue(q + 3, wB, hB, tB);
            }
        }
    }
    *(float4*)&sPart[wid][c4] = acc;
    __syncthreads();
    agg[i * H + tid] = sPart[0][tid] + sPart[1][tid] + sPart[2][tid] + sPart[3][tid];
}

// Atom MLP: hout = hin + gelu(agg@aw1+ab1)@aw2+ab2 (also emits fp16 mirror).
// 512 threads = 8 waves; waves split K into eighths (32 rows each).
__global__ void __launch_bounds__(512) mlp_k(
    const float* __restrict__ agg, const float* __restrict__ hin,
    const float* __restrict__ aw1, const float* __restrict__ ab1,
    const float* __restrict__ aw2, const float* __restrict__ ab2,
    float* __restrict__ hout, __half* __restrict__ hhf_out) {
    int tid = threadIdx.x;
    int wid = tid >> 6, lane = tid & 63;
    int c4 = lane * 4;
    int i0 = blockIdx.x * MATB;
    __shared__ __align__(16) float sAT[H][MATB];   // acts transposed [k][a]
    __shared__ __align__(16) float sGT[H][MATB];
    __shared__ __align__(16) float sPart[8][MATB][H];  // 32 KB

    if (tid < H) {
        #pragma unroll
        for (int r = 0; r < MATB; ++r)
            sAT[tid][r] = agg[(i0 + r) * H + tid];
    }
    __syncthreads();

    int k0 = wid * 32;
    float4 acc[MATB];
    #pragma unroll
    for (int a = 0; a < MATB; ++a) acc[a] = make_float4(0.f, 0.f, 0.f, 0.f);
    #pragma unroll 8
    for (int k = 0; k < 32; ++k) {
        float4 q = *(const float4*)(aw1 + (k0 + k) * H + c4);
        float4 act = *(const float4*)&sAT[k0 + k][0];
        FMA4(acc[0], act.x, q); FMA4(acc[1], act.y, q);
        FMA4(acc[2], act.z, q); FMA4(acc[3], act.w, q);
    }
    #pragma unroll
    for (int a = 0; a < MATB; ++a)
        *(float4*)&sPart[wid][a][c4] = acc[a];
    __syncthreads();
    if (tid < H) {
        float b1 = ab1[tid];
        float g[MATB];
        #pragma unroll
        for (int a = 0; a < MATB; ++a) {
            float v = b1;
            #pragma unroll
            for (int s = 0; s < 8; ++s) v += sPart[s][a][tid];
            g[a] = gelu_f(v);
        }
        *(float4*)&sGT[tid][0] = make_float4(g[0], g[1], g[2], g[3]);
    }
    __syncthreads();
    #pragma unroll
    for (int a = 0; a < MATB; ++a) acc[a] = make_float4(0.f, 0.f, 0.f, 0.f);
    #pragma unroll 8
    for (int k = 0; k < 32; ++k) {
        float4 q = *(const float4*)(aw2 + (k0 + k) * H + c4);
        float4 act = *(const float4*)&sGT[k0 + k][0];
        FMA4(acc[0], act.x, q); FMA4(acc[1], act.y, q);
        FMA4(acc[2], act.z, q); FMA4(acc[3], act.w, q);
    }
    #pragma unroll
    for (int a = 0; a < MATB; ++a)
        *(float4*)&sPart[wid][a][c4] = acc[a];
    __syncthreads();
    if (tid < H) {
        float b2 = ab2[tid];
        #pragma unroll
        for (int a = 0; a < MATB; ++a) {
            float v = b2;
            #pragma unroll
            for (int s = 0; s < 8; ++s) v += sPart[s][a][tid];
            float hv = hin[(i0 + a) * H + tid] + v;
            hout[(i0 + a) * H + tid] = hv;
            hhf_out[(i0 + a) * H + tid] = __float2half(hv);
        }
    }
}

// pooled -> gelu(pw1) -> pw2 -> layernorm. Block per molecule, waves split K.
__global__ void __launch_bounds__(256) head_k(
        const float* __restrict__ h,
        const float* __restrict__ pw1, const float* __restrict__ pb1,
        const float* __restrict__ pw2, const float* __restrict__ pb2,
        const float* __restrict__ ln_g, const float* __restrict__ ln_b,
        float* __restrict__ out) {
    int b = blockIdx.x, tid = threadIdx.x;
    int wid = tid >> 6, lane = tid & 63;
    int c4 = lane * 4;
    __shared__ float sP[H];
    __shared__ __align__(16) float sPw[4][H];
    __shared__ float sG[H];
    __shared__ __align__(16) float sP2[4][L];
    __shared__ float sX[L];
    __shared__ float sRed[256];

    float4 p = make_float4(0.f, 0.f, 0.f, 0.f);
    #pragma unroll 4
    for (int a = 0; a < 16; ++a) {
        float4 hv = *(const float4*)(h + (b * 64 + wid * 16 + a) * H + c4);
        p.x += hv.x; p.y += hv.y; p.z += hv.z; p.w += hv.w;
    }
    *(float4*)&sPw[wid][c4] = p;
    __syncthreads();
    sP[tid] = sPw[0][tid] + sPw[1][tid] + sPw[2][tid] + sPw[3][tid];
    __syncthreads();

    int k0 = wid * 64;
    float4 acc = make_float4(0.f, 0.f, 0.f, 0.f);
    #pragma unroll 8
    for (int k = 0; k < 64; ++k) {
        float4 q = *(const float4*)(pw1 + (k0 + k) * H + c4);
        float s = sP[k0 + k];
        FMA4(acc, s, q);
    }
    *(float4*)&sPw[wid][c4] = acc;
    __syncthreads();
    sG[tid] = gelu_f(pb1[tid] + sPw[0][tid] + sPw[1][tid] + sPw[2][tid] + sPw[3][tid]);
    __syncthreads();

    float4 a0 = make_float4(0.f, 0.f, 0.f, 0.f);
    float4 a1 = make_float4(0.f, 0.f, 0.f, 0.f);
    #pragma unroll 4
    for (int k = 0; k < 64; ++k) {
        float s = sG[k0 + k];
        float4 q0 = *(const float4*)(pw2 + (k0 + k) * L + lane * 8);
        float4 q1 = *(const float4*)(pw2 + (k0 + k) * L + lane * 8 + 4);
        FMA4(a0, s, q0);
        FMA4(a1, s, q1);
    }
    *(float4*)&sP2[wid][lane * 8] = a0;
    *(float4*)&sP2[wid][lane * 8 + 4] = a1;
    __syncthreads();
    for (int r = 0; r < 2; ++r) {
        int l = tid + r * 256;
        sX[l] = pb2[l] + sP2[0][l] + sP2[1][l] + sP2[2][l] + sP2[3][l];
    }
    __syncthreads();

    sRed[tid] = sX[tid] + sX[tid + 256];
    __syncthreads();
    for (int off = 128; off > 0; off >>= 1) {
        if (tid < off) sRed[tid] += sRed[tid + off];
        __syncthreads();
    }
    float mu = sRed[0] / (float)L;
    __syncthreads();
    float d0 = sX[tid] - mu, d1 = sX[tid + 256] - mu;
    sRed[tid] = d0 * d0 + d1 * d1;
    __syncthreads();
    for (int off = 128; off > 0; off >>= 1) {
        if (tid < off) sRed[tid] += sRed[tid + off];
        __syncthreads();
    }
    float var = sRed[0] / (float)L;
    float rstd = rsqrtf(var + 1e-5f);
    for (int r = 0; r < 2; ++r) {
        int l = tid + r * 256;
        out[b * L + l] = (sX[l] - mu) * rstd * ln_g[l] + ln_b[l];
    }
}

extern "C" void kernel_launch(void* const* d_in, const int* in_sizes, int n_in,
                              void* d_out, int out_size, void* d_ws, size_t ws_size,
                              hipStream_t stream) {
    const int*   z    = (const int*)d_in[0];
    const float* pos  = (const float*)d_in[1];
    // d_in[2] = batch: fixed arange//64 layout, handled implicitly in head_k
    const float* emb  = (const float*)d_in[3];
    const float* fw1  = (const float*)d_in[4];
    const float* fb1  = (const float*)d_in[5];
    const float* fw2  = (const float*)d_in[6];
    const float* fb2  = (const float*)d_in[7];
    const float* aw1  = (const float*)d_in[8];
    const float* ab1  = (const float*)d_in[9];
    const float* aw2  = (const float*)d_in[10];
    const float* ab2  = (const float*)d_in[11];
    const float* pw1  = (const float*)d_in[12];
    const float* pb1  = (const float*)d_in[13];
    const float* pw2  = (const float*)d_in[14];
    const float* pb2  = (const float*)d_in[15];
    const float* ln_g = (const float*)d_in[16];
    const float* ln_b = (const float*)d_in[17];
    float* out = (float*)d_out;

    float* hA  = (float*)d_ws;                        // [N][H] fp32
    float* hB  = hA + N * H;                          // [N][H] fp32
    float* agg = hB + N * H;                          // [N][H] fp32
    __half* hhfA = (__half*)(agg + N * H);            // [N][H] fp16
    __half* hhfB = hhfA + N * H;                      // [N][H] fp16
    __half* Wtb  = hhfB + N * H;                      // [NI][TROWS][H] fp16
    __half2* Wp = (__half2*)(Wtb + (size_t)NI * TROWS * H);   // [NI][PROWS][H]
    float2* meta = (float2*)(Wp + (size_t)NI * PROWS * H);    // [N][CAP]
    int* cnts = (int*)(meta + (size_t)N * CAP);               // [N]
    unsigned short* Bt = (unsigned short*)(cnts + N);         // [NI][H][H] bf16

    embed_k<<<N, H, 0, stream>>>(z, emb, hA, hhfA);
    nbrbuild_k<<<N, 256, 0, stream>>>(pos, meta, cnts);
    bweights_k<<<NI * H, 256, 0, stream>>>(fw2, Bt);
    {
        int bpl = (TROWS + BPB - 1) / BPB;
        table_k<<<NI * bpl, 256, 0, stream>>>(fw1, fb1, Bt, fb2, Wtb);
        pack_k<<<NI * PROWS, 256, 0, stream>>>(Wtb, Wp);
    }
    float* hin = hA;  __half* hbin = hhfA;
    float* hout = hB; __half* hbout = hhfB;
    for (int it = 0; it < NI; ++it) {
        pair_k<<<N, 256, 0, stream>>>(hbin, (const unsigned*)(Wp + (size_t)it * PROWS * H),
                                      meta, cnts, agg);
        mlp_k<<<N / MATB, 512, 0, stream>>>(agg, hin, aw1 + it * H * H, ab1 + it * H,
                                            aw2 + it * H * H, ab2 + it * H, hout, hbout);
        float* t1 = hin; hin = hout; hout = t1;
        __half* t2 = hbin; hbin = hbout; hbout = t2;
    }
    head_k<<<B, 256, 0, stream>>>(hin, pw1, pb1, pw2, pb2, ln_g, ln_b, out);
}